// Round 17
// baseline (4795.668 us; speedup 1.0000x reference)
//
#include <hip/hip_runtime.h>

#define DEV __device__ __forceinline__

typedef __attribute__((ext_vector_type(4))) int i32x4;
typedef __attribute__((ext_vector_type(4))) double f64x4;

// ---------------------------------------------------------------------------
// TernaryMVAdapter forward on MI355X. Round 17: round-16 (4212us) +
//  * k_dgemm 64x128 tile at BK=16: LDS 26.1KB -> 6 blocks/CU by LDS (4 by
//    VGPR) ~50% occupancy AND 0.75 LDS-read/MFMA (r14's ratio without its
//    occupancy collapse). Per-acc k-order sequential -> bitwise identical.
//  * register prefetch of next K-tile's staging loads (HBM latency hidden
//    under MFMA phase; staging content unchanged).
// ---------------------------------------------------------------------------

struct WList { const float* p[37]; long long n[37]; };
struct WOffs { long long o[37]; };
struct W3 { const signed char* w[3]; const double* sc[3]; double* c[3]; };
struct W9 { const signed char* w[9]; const double* sc[9]; double* c[9]; };

DEV int2 xcd_swz(int gridx)
{
    const int nwg = (int)gridDim.x, b = (int)blockIdx.x;
    const int q = nwg >> 3, r = nwg & 7, xcd = b & 7, idx = b >> 3;
    const int lb = (xcd < r ? xcd*(q+1) : r*(q+1) + (xcd-r)*q) + idx;
    return make_int2(lb % gridx, lb / gridx);
}

// ---------------- f64 MFMA layout probe (exact-integer classification) -----
__global__ void k_mfma64_probe(double* __restrict__ out)
{
    const int lane = threadIdx.x;                      // 64 threads
    double a = (double)(1 + lane);
    double b = (double)(101 + 3*lane);
    f64x4 acc = {0.0, 0.0, 0.0, 0.0};
    acc = __builtin_amdgcn_mfma_f64_16x16x4f64(a, b, acc, 0, 0, 0);
#pragma unroll
    for (int r = 0; r < 4; ++r) out[lane*4 + r] = acc[r];
}

__global__ void k_mfma64_check(const double* __restrict__ probe, int* __restrict__ flag)
{
    if (threadIdx.x != 0) return;
    int best = 0;
    for (int c = 0; c < 16 && !best; ++c) {
        const int a_alt = c & 1, b_alt = (c >> 1) & 1, dv = (c >> 2) & 3;
        double Amat[16][4], Bmat[4][16];
        for (int l = 0; l < 64; ++l) {
            int ai = a_alt ? (l >> 2) : (l & 15);
            int ak = a_alt ? (l & 3)  : (l >> 4);
            Amat[ai][ak] = (double)(1 + l);
            int bj = b_alt ? (l >> 2) : (l & 15);
            int bk = b_alt ? (l & 3)  : (l >> 4);
            Bmat[bk][bj] = (double)(101 + 3*l);
        }
        double C[16][16];
        for (int i = 0; i < 16; ++i)
            for (int j = 0; j < 16; ++j) {
                double s = 0.0;
                for (int k = 0; k < 4; ++k) s += Amat[i][k] * Bmat[k][j];
                C[i][j] = s;
            }
        bool ok = true;
        for (int l = 0; l < 64 && ok; ++l)
            for (int r = 0; r < 4 && ok; ++r) {
                int ir = (dv & 2) ? (4*r + (l >> 4)) : (4*(l >> 4) + r);
                int ic = l & 15;
                if (dv & 1) { int t = ir; ir = ic; ic = t; }
                if (probe[l*4 + r] != C[ir][ic]) ok = false;
            }
        if (ok) best = 1 + c;
    }
    *flag = best;
}

// ---------------- fused deterministic |w| sums (37 slots) ------------------
__global__ void k_abssum_all(WList wl, double* __restrict__ partials)
{
    const int slot = blockIdx.y;
    const float* w = wl.p[slot];
    const long long n = wl.n[slot];
    __shared__ double sm[256];
    double s = 0.0;
    for (long long i = (long long)blockIdx.x*256 + threadIdx.x; i < n; i += 32LL*256)
        s += (double)fabsf(w[i]);
    sm[threadIdx.x] = s;
    __syncthreads();
    for (int k = 128; k > 0; k >>= 1) {
        if ((int)threadIdx.x < k) sm[threadIdx.x] += sm[threadIdx.x + k];
        __syncthreads();
    }
    if (threadIdx.x == 0) partials[slot*32 + blockIdx.x] = sm[0];
}

__global__ void k_abssum_fin(const double* __restrict__ partials, double* __restrict__ out)
{
    const int slot = blockIdx.x;
    if (threadIdx.x == 0) {
        double s = 0.0;
        for (int i = 0; i < 32; ++i) s += partials[slot*32 + i];
        out[slot] = s;
    }
}

// ---------------- one-time weight ternarization (f64-exact decision) -------
__global__ void k_ternarize(WList wl, WOffs wo, const double* __restrict__ scales,
                            signed char* __restrict__ W8)
{
    const int slot = blockIdx.y;
    const float* w = wl.p[slot];
    const long long n4 = wl.n[slot] >> 2;
    const double dqw = fmax(scales[slot] / (double)wl.n[slot], 1e-5);
    const double thr = 0.5 * dqw;
    signed char* o = W8 + wo.o[slot];
    for (long long i = (long long)blockIdx.x*256 + threadIdx.x; i < n4; i += 64LL*256) {
        float4 v = *reinterpret_cast<const float4*>(w + i*4);
        float we[4] = {v.x, v.y, v.z, v.w};
        char r[4];
#pragma unroll
        for (int e = 0; e < 4; ++e) {
            double wd = (double)we[e];
            r[e] = (char)((wd > thr) - (wd < -thr));
        }
        *reinterpret_cast<char4*>(o + i*4) = make_char4(r[0], r[1], r[2], r[3]);
    }
}

// ---------------- sa_dc_w pre-transpose to linear k' -----------------------
__global__ void k_dcw_prep(const float* __restrict__ w, float* __restrict__ wt)
{
    int row = blockIdx.x;                              // 1152
    for (int k = threadIdx.x; k < 4608; k += 256) {
        int q = k / 1152, c = k - q*1152;
        wt[(size_t)row*4608 + k] = w[(size_t)row*4608 + (size_t)c*4 + q];
    }
}

// ---------------- timestep frequency embedding (f64) -----------------------
__global__ void k_temb(const float* __restrict__ t, double* __restrict__ out)
{
    int b = blockIdx.x, j = threadIdx.x;               // 8 x 128
    double fr  = exp(-9.210340371976184 * (double)j / 128.0);
    double ang = (double)t[b] * fr;
    out[b*256 + j]       = cos(ang);
    out[b*256 + 128 + j] = sin(ang);
}

// ---------------- rmsnorm + int8 absmax quant (f64, LDS-free) --------------
template<typename TI>
__global__ void k_rsq8(const TI* __restrict__ x, signed char* __restrict__ q8,
                       double* __restrict__ dscale, int K, int pre_silu)
{
    __shared__ double red[256], red2[256];
    const int row = blockIdx.x, tid = threadIdx.x;
    const TI* xr = x + (size_t)row*K;
    double ss = 0.0, am = 0.0;
    for (int i = tid; i < K; i += 256) {
        double v = (double)xr[i];
        if (pre_silu) v = v / (1.0 + exp(-v));
        ss += v*v; am = fmax(am, fabs(v));
    }
    red[tid] = ss; red2[tid] = am;
    __syncthreads();
    for (int s = 128; s > 0; s >>= 1) {
        if (tid < s) { red[tid] += red[tid+s]; red2[tid] = fmax(red2[tid], red2[tid+s]); }
        __syncthreads();
    }
    double rms = 1.0 / sqrt(red[0]/(double)K + 1e-8);
    double s   = 127.0 / fmax(red2[0]*rms, 1e-5);
    signed char* orow = q8 + (size_t)row*K;
    for (int i = tid; i < K; i += 256) {
        double v = (double)xr[i];
        if (pre_silu) v = v / (1.0 + exp(-v));
        orow[i] = (signed char)(int)fmin(fmax(rint(v*rms*s), -128.0), 127.0);
    }
    if (tid == 0) dscale[row] = s;
}

// LDS-cached single-read variant (for K=4608: avoids 2nd 151MB HBM pass)
__global__ void k_rsq8c(const double* __restrict__ x, signed char* __restrict__ q8,
                        double* __restrict__ dscale, int K)
{
    extern __shared__ double rb[];
    __shared__ double red[256], red2[256];
    const int row = blockIdx.x, tid = threadIdx.x;
    const double* xr = x + (size_t)row*K;
    double ss = 0.0, am = 0.0;
    for (int i = tid; i < K; i += 256) {
        double v = xr[i];
        rb[i] = v; ss += v*v; am = fmax(am, fabs(v));
    }
    red[tid] = ss; red2[tid] = am;
    __syncthreads();
    for (int s = 128; s > 0; s >>= 1) {
        if (tid < s) { red[tid] += red[tid+s]; red2[tid] = fmax(red2[tid], red2[tid+s]); }
        __syncthreads();
    }
    double rms = 1.0 / sqrt(red[0]/(double)K + 1e-8);
    double s   = 127.0 / fmax(red2[0]*rms, 1e-5);
    signed char* orow = q8 + (size_t)row*K;
    for (int i = tid; i < K; i += 256)
        orow[i] = (signed char)(int)fmin(fmax(rint(rb[i]*rms*s), -128.0), 127.0);
    if (tid == 0) dscale[row] = s;
}

// ---------------- layernorm(+gb/+mod) + rmsnorm + int8 quant (f64) ---------
__global__ void k_lnq8(const double* __restrict__ x, signed char* __restrict__ q8,
                       double* __restrict__ dscale, int K,
                       const float* __restrict__ gamma, const float* __restrict__ beta,
                       const double* __restrict__ sh, const double* __restrict__ sc,
                       int modstride, double eps)
{
    extern __shared__ double rb[];
    __shared__ double red[256], red2[256];
    const int row = blockIdx.x, tid = threadIdx.x;
    const double* xr = x + (size_t)row*K;
    double s1 = 0.0;
    for (int i = tid; i < K; i += 256) { double v = xr[i]; rb[i] = v; s1 += v; }
    red[tid] = s1; __syncthreads();
    for (int s = 128; s > 0; s >>= 1) { if (tid < s) red[tid] += red[tid+s]; __syncthreads(); }
    double mu = red[0]/(double)K;
    __syncthreads();
    double s2 = 0.0;
    for (int i = tid; i < K; i += 256) { double d = rb[i]-mu; s2 += d*d; }
    red[tid] = s2; __syncthreads();
    for (int s = 128; s > 0; s >>= 1) { if (tid < s) red[tid] += red[tid+s]; __syncthreads(); }
    double r = 1.0 / sqrt(red[0]/(double)K + eps);
    const int bn = row >> 8;
    __syncthreads();
    double ss = 0.0, am = 0.0;
    for (int i = tid; i < K; i += 256) {
        double y = (rb[i]-mu)*r;
        if (gamma) y = y*(double)gamma[i] + (double)beta[i];
        if (sh)    y = y*(1.0 + sc[(size_t)bn*modstride + i]) + sh[(size_t)bn*modstride + i];
        rb[i] = y; ss += y*y; am = fmax(am, fabs(y));
    }
    red[tid] = ss; red2[tid] = am;
    __syncthreads();
    for (int s = 128; s > 0; s >>= 1) {
        if (tid < s) { red[tid] += red[tid+s]; red2[tid] = fmax(red2[tid], red2[tid+s]); }
        __syncthreads();
    }
    double rms = 1.0 / sqrt(red[0]/(double)K + 1e-8);
    double s   = 127.0 / fmax(red2[0]*rms, 1e-5);
    signed char* orow = q8 + (size_t)row*K;
    for (int i = tid; i < K; i += 256)
        orow[i] = (signed char)(int)fmin(fmax(rint(rb[i]*rms*s), -128.0), 127.0);
    if (tid == 0) dscale[row] = s;
}

// ---------------- ogate (rmsnorm*g*sig(g)) + rmsnorm + quant (f64) ---------
__global__ void k_ogateq8(const double* __restrict__ O, const double* __restrict__ G,
                          signed char* __restrict__ q8, double* __restrict__ dscale, int K)
{
    extern __shared__ double rb[];
    __shared__ double red[256], red2[256];
    const int row = blockIdx.x, tid = threadIdx.x;
    const double* orow = O + (size_t)row*K;
    const double* grow = G + (size_t)row*K;
    double ss = 0.0;
    for (int i = tid; i < K; i += 256) { double v = orow[i]; rb[i] = v; ss += v*v; }
    red[tid] = ss; __syncthreads();
    for (int s = 128; s > 0; s >>= 1) { if (tid < s) red[tid] += red[tid+s]; __syncthreads(); }
    double rmso = 1.0 / sqrt(red[0]/(double)K + 1e-8);
    __syncthreads();
    double ss2 = 0.0, am = 0.0;
    for (int i = tid; i < K; i += 256) {
        double g = grow[i];
        double y = rb[i]*rmso * g / (1.0 + exp(-g));
        rb[i] = y; ss2 += y*y; am = fmax(am, fabs(y));
    }
    red[tid] = ss2; red2[tid] = am;
    __syncthreads();
    for (int s = 128; s > 0; s >>= 1) {
        if (tid < s) { red[tid] += red[tid+s]; red2[tid] = fmax(red2[tid], red2[tid+s]); }
        __syncthreads();
    }
    double rms = 1.0 / sqrt(red[0]/(double)K + 1e-8);
    double s   = 127.0 / fmax(red2[0]*rms, 1e-5);
    signed char* qrow = q8 + (size_t)row*K;
    for (int i = tid; i < K; i += 256)
        qrow[i] = (signed char)(int)fmin(fmax(rint(rb[i]*rms*s), -128.0), 127.0);
    if (tid == 0) dscale[row] = s;
}

// combined ogate: rows 0..2047 self, 2048..4095 mv, 4096..4607 ref (K=1152)
__global__ void k_ogateq8c3(const double* __restrict__ Os, const double* __restrict__ Gs,
                            const double* __restrict__ Om, const double* __restrict__ Gm,
                            const double* __restrict__ Or, const double* __restrict__ Gr,
                            signed char* __restrict__ q8, double* __restrict__ dscale)
{
    extern __shared__ double rb[];
    __shared__ double red[256], red2[256];
    const int row = blockIdx.x, tid = threadIdx.x;
    const int K = 1152;
    const double *orow, *grow;
    if (row < 2048)      { orow = Os + (size_t)row*K;        grow = Gs + (size_t)row*K; }
    else if (row < 4096) { orow = Om + (size_t)(row-2048)*K; grow = Gm + (size_t)(row-2048)*K; }
    else                 { orow = Or + (size_t)(row-4096)*K; grow = Gr + (size_t)(row-4096)*K; }
    double ss = 0.0;
    for (int i = tid; i < K; i += 256) { double v = orow[i]; rb[i] = v; ss += v*v; }
    red[tid] = ss; __syncthreads();
    for (int s = 128; s > 0; s >>= 1) { if (tid < s) red[tid] += red[tid+s]; __syncthreads(); }
    double rmso = 1.0 / sqrt(red[0]/(double)K + 1e-8);
    __syncthreads();
    double ss2 = 0.0, am = 0.0;
    for (int i = tid; i < K; i += 256) {
        double g = grow[i];
        double y = rb[i]*rmso * g / (1.0 + exp(-g));
        rb[i] = y; ss2 += y*y; am = fmax(am, fabs(y));
    }
    red[tid] = ss2; red2[tid] = am;
    __syncthreads();
    for (int s = 128; s > 0; s >>= 1) {
        if (tid < s) { red[tid] += red[tid+s]; red2[tid] = fmax(red2[tid], red2[tid+s]); }
        __syncthreads();
    }
    double rms = 1.0 / sqrt(red[0]/(double)K + 1e-8);
    double s   = 127.0 / fmax(red2[0]*rms, 1e-5);
    signed char* qrow = q8 + (size_t)row*K;
    for (int i = tid; i < K; i += 256)
        qrow[i] = (signed char)(int)fmin(fmax(rint(rb[i]*rms*s), -128.0), 127.0);
    if (tid == 0) dscale[row] = s;
}

// ---------------- HGRN scans -----------------------------------------------
__global__ void k_gatepre(double* __restrict__ F, double* __restrict__ I, long long n)
{
    long long i = (long long)blockIdx.x*256 + threadIdx.x;
    if (i >= n) return;
    double fp = F[i], ip = I[i];
    double f = 1.0/(1.0+exp(-fp));
    double v = (ip/(1.0+exp(-ip)))*(1.0-f);
    F[i] = f; I[i] = v;
}

__global__ void k_scan2(const double* __restrict__ F, const double* __restrict__ V,
                        double* __restrict__ O, int n_outer, long long outer_stride,
                        int n_inner, long long t_stride, int T)
{
    long long chain = (long long)blockIdx.x*blockDim.x + threadIdx.x;
    if (chain >= (long long)n_outer*n_inner) return;
    long long base = (chain / n_inner)*outer_stride + (chain % n_inner);
    double h = 0.0;
    for (int t = 0; t < T; ++t) {
        long long idx = base + (long long)t*t_stride;
        h = F[idx]*h + V[idx];
        O[idx] = h;
    }
}

__global__ void k_scan3(const double* __restrict__ F, const double* __restrict__ Isilu,
                        double* __restrict__ O, int n_outer, long long outer_stride,
                        int n_inner, long long t_stride, int T)
{
    long long chain = (long long)blockIdx.x*blockDim.x + threadIdx.x;
    if (chain >= (long long)n_outer*n_inner) return;
    long long base = (chain / n_inner)*outer_stride + (chain % n_inner);
    double h = 0.0;
    for (int t = 0; t < T; ++t) {
        long long idx = base + (long long)t*t_stride;
        double f = F[idx];
        double v = Isilu[idx]*(1.0-f);
        h = f*h + v;
        O[idx] = h;
    }
}

// combined self+mv+ref scan:
// chains [0,9216) self T=256; [9216, 9216+589824) mv T=4; rest ref T=256
__global__ void k_scanc3(const double* __restrict__ Fs, const double* __restrict__ Is,
                         const double* __restrict__ Fm, const double* __restrict__ Im,
                         const double* __restrict__ Fr, const double* __restrict__ Ir,
                         double* __restrict__ Osf, double* __restrict__ Omv,
                         double* __restrict__ Orf)
{
    long long cid = (long long)blockIdx.x*blockDim.x + threadIdx.x;
    if (cid < 9216) {
        long long base = (cid / 1152)*294912LL + (cid % 1152);
        double h = 0.0;
        for (int t = 0; t < 256; ++t) {
            long long idx = base + (long long)t*1152;
            double f = Fs[idx];
            double v = Is[idx]*(1.0-f);
            h = f*h + v;
            Osf[idx] = h;
        }
    } else if (cid < 9216 + 589824LL) {
        long long c2 = cid - 9216;
        long long base = (c2 / 294912)*1179648LL + (c2 % 294912);
        double h = 0.0;
        for (int t = 0; t < 4; ++t) {
            long long idx = base + (long long)t*294912;
            double f = Fm[idx];
            double v = Im[idx]*(1.0-f);
            h = f*h + v;
            Omv[idx] = h;
        }
    } else {
        long long c3 = cid - 9216 - 589824LL;
        if (c3 >= 2304) return;
        long long base = (c3 / 1152)*294912LL + (c3 % 1152);
        double h = 0.0;
        for (int t = 0; t < 256; ++t) {
            long long idx = base + (long long)t*1152;
            double f = Fr[idx];
            double v = Ir[idx]*(1.0-f);
            h = f*h + v;
            Orf[idx] = h;
        }
    }
}

// ---------------- misc elementwise (f64) -----------------------------------
__global__ void k_add(const double* __restrict__ a, const double* __restrict__ b,
                      double* __restrict__ o, int n)
{
    int i = blockIdx.x*256 + threadIdx.x;
    if (i < n) o[i] = a[i] + b[i];
}

__global__ void k_resid_attn(double* __restrict__ xt, const double* __restrict__ acc,
                             const double* __restrict__ refo, const double* __restrict__ mod)
{
    int idx = blockIdx.x*256 + threadIdx.x;            // 2048*1152 exact
    int r = idx / 1152, d = idx - r*1152;
    int bn = r >> 8, l = r & 255;
    double ga = mod[(size_t)bn*6912 + 2*1152 + d];
    double rv = refo[((size_t)((bn>>2)*256 + l))*1152 + d];
    xt[idx] += ga*(acc[idx] + rv);
}

// fused-path residual: ga*((self+mv)+ref) — same add order as old accum path
__global__ void k_resid_attn2(double* __restrict__ xt, const double* __restrict__ acc,
                              const double* __restrict__ mvb, const double* __restrict__ refo,
                              const double* __restrict__ mod)
{
    int idx = blockIdx.x*256 + threadIdx.x;            // 2048*1152 exact
    int r = idx / 1152, d = idx - r*1152;
    int bn = r >> 8, l = r & 255;
    double ga = mod[(size_t)bn*6912 + 2*1152 + d];
    double rv = refo[((size_t)((bn>>2)*256 + l))*1152 + d];
    xt[idx] += ga*((acc[idx] + mvb[idx]) + rv);
}

__global__ void k_resid_mlp(double* __restrict__ xt, const double* __restrict__ t2,
                            const double* __restrict__ mod)
{
    int idx = blockIdx.x*256 + threadIdx.x;
    int r = idx / 1152, d = idx - r*1152;
    int bn = r >> 8;
    xt[idx] += mod[(size_t)bn*6912 + 5*1152 + d] * t2[idx];
}

__global__ void k_patchify(const float* __restrict__ x, const float* __restrict__ w,
                           const float* __restrict__ bias, const float* __restrict__ pos,
                           const double* __restrict__ f0, double* __restrict__ xt)
{
    int idx = blockIdx.x*256 + threadIdx.x;            // 2048*1152 exact
    int r = idx / 1152, o = idx - r*1152;
    int bn = r >> 8, p = r & 255;
    int y = p >> 4, xx = p & 15;
    double acc = (double)bias[o] + (double)pos[(size_t)p*1152 + o] + f0[idx];
#pragma unroll
    for (int c = 0; c < 4; ++c)
#pragma unroll
        for (int ky = 0; ky < 2; ++ky)
#pragma unroll
            for (int kx = 0; kx < 2; ++kx)
                acc += (double)x[((size_t)(bn*4 + c)*32 + 2*y+ky)*32 + 2*xx+kx]
                     * (double)w[o*16 + c*4 + ky*2 + kx];
    xt[idx] = acc;
}

__global__ void k_unpatch(const double* __restrict__ flo, float* __restrict__ out)
{
    int idx = blockIdx.x*256 + threadIdx.x;            // 65536 exact
    int xx = idx & 31, y = (idx>>5)&31, ch = (idx>>10)&7, b = idx>>13;
    int hp = y>>1, py = y&1, wp = xx>>1, px = xx&1;
    out[idx] = (float)flo[((size_t)(b*256 + hp*16 + wp))*32 + (py*2+px)*8 + ch];
}

// ---------------- f64 GEMM: probed MFMA (64x128, BK=16, prefetch) ----------
template<int AMODE>
DEV void load_a4d(const void* __restrict__ A, int row, int k, int M, double o[4])
{
    if (row >= M) { o[0]=o[1]=o[2]=o[3]=0.0; return; }
    if constexpr (AMODE == 1) {
        const float* Af = (const float*)A;
        int b = row>>10, p = row&1023, oy = p>>5, ox = p&31;
        int c = k>>8, ky = (k>>4)&15, kx = k&15;
        float4 v = *reinterpret_cast<const float4*>(
            Af + (((size_t)(b*6+c)*512 + (size_t)(oy*16+ky))*512 + (size_t)(ox*16+kx)));
        o[0]=v.x; o[1]=v.y; o[2]=v.z; o[3]=v.w;
    } else {
        const double* Ad = (const double*)A;
        int b = row>>8, y = (row>>4)&15, x = row&15;
        int q = k/1152, c = k - q*1152, ky = q>>1, kx = q&1;
        const double* p = Ad + (size_t)(b*1024 + (2*y+ky)*32 + 2*x+kx)*1152 + c;
        o[0]=p[0]; o[1]=p[1]; o[2]=p[2]; o[3]=p[3];
    }
}

template<int WMODE>
DEV void load_w4d(const float* __restrict__ W, int row, int k, int Nb, int K, double o[4])
{
    if (row >= Nb) { o[0]=o[1]=o[2]=o[3]=0.0; return; }
    if constexpr (WMODE == 0) {
        float4 v = *reinterpret_cast<const float4*>(W + (size_t)row*K + k);
        o[0]=v.x; o[1]=v.y; o[2]=v.z; o[3]=v.w;
    } else {
        int q = k/1152, c = k - q*1152;
        const float* p = W + (size_t)row*4608 + (size_t)c*4 + q;
        o[0]=p[0]; o[1]=p[4]; o[2]=p[8]; o[3]=p[12];
    }
}

template<int AMODE, int WMODE>
__global__ __launch_bounds__(256)
void k_dgemm(const void* __restrict__ A, const float* __restrict__ W,
             const float* __restrict__ bias, double* __restrict__ C,
             int M, int N, int K, int gridx, const int* __restrict__ mfma_flag)
{
    __shared__ double As[64][17];                  // [m][k0..15], +1 pad
    __shared__ double Ws[128][17];                 // [n0..127][k0..15]
    const int tid = threadIdx.x;
    const int2 bxy = xcd_swz(gridx);
    const int m0 = bxy.y*64, n0 = bxy.x*128;
    const int lr = tid >> 2;                       // A staging row 0..63
    const int lc = (tid & 3) * 4;                  // A staging k {0,4,8,12}
    const int wrow = tid >> 1;                     // W staging row 0..127
    const int wkh = (tid & 1) * 8;                 // W staging k base {0,8}
    const int flag = *mfma_flag;                   // uniform

    if (flag) {
        const int cmb = flag - 1;
        const int a_alt = cmb & 1, b_alt = (cmb >> 1) & 1, dv = (cmb >> 2) & 3;
        const int lane = tid & 63, wid = tid >> 6;
        const int wm = wid >> 1, wn = wid & 1;     // 2x2 waves of 32x64
        const int ai = a_alt ? (lane >> 2) : (lane & 15);
        const int ak = a_alt ? (lane & 3)  : (lane >> 4);
        const int bj = b_alt ? (lane >> 2) : (lane & 15);
        const int bk = b_alt ? (lane & 3)  : (lane >> 4);
        f64x4 fa[2][4];
#pragma unroll
        for (int i = 0; i < 2; ++i)
#pragma unroll
            for (int j = 0; j < 4; ++j) fa[i][j] = f64x4{0.0,0.0,0.0,0.0};

        // register prefetch of tile 0
        double pa[4], pw0[4], pw1[4];
        load_a4d<AMODE>(A, m0+lr, lc, M, pa);
        load_w4d<WMODE>(W, n0+wrow, wkh, N, K, pw0);
        load_w4d<WMODE>(W, n0+wrow, wkh+4, N, K, pw1);

        for (int kt = 0; kt < K; kt += 16) {
            As[lr][lc+0]=pa[0]; As[lr][lc+1]=pa[1]; As[lr][lc+2]=pa[2]; As[lr][lc+3]=pa[3];
            Ws[wrow][wkh+0]=pw0[0]; Ws[wrow][wkh+1]=pw0[1];
            Ws[wrow][wkh+2]=pw0[2]; Ws[wrow][wkh+3]=pw0[3];
            Ws[wrow][wkh+4]=pw1[0]; Ws[wrow][wkh+5]=pw1[1];
            Ws[wrow][wkh+6]=pw1[2]; Ws[wrow][wkh+7]=pw1[3];
            __syncthreads();
            if (kt + 16 < K) {                      // issue next tile's loads
                load_a4d<AMODE>(A, m0+lr, kt+16+lc, M, pa);
                load_w4d<WMODE>(W, n0+wrow, kt+16+wkh, N, K, pw0);
                load_w4d<WMODE>(W, n0+wrow, kt+16+wkh+4, N, K, pw1);
            }
#pragma unroll
            for (int k4 = 0; k4 < 4; ++k4) {        // sequential k order preserved
                double a0 = As[wm*32 + ai][k4*4 + ak];
                double a1 = As[wm*32 + 16 + ai][k4*4 + ak];
                double b[4];
#pragma unroll
                for (int j = 0; j < 4; ++j) b[j] = Ws[wn*64 + j*16 + bj][k4*4 + bk];
#pragma unroll
                for (int j = 0; j < 4; ++j) {
                    fa[0][j] = __builtin_amdgcn_mfma_f64_16x16x4f64(a0, b[j], fa[0][j], 0, 0, 0);
                    fa[1][j] = __builtin_amdgcn_mfma_f64_16x16x4f64(a1, b[j], fa[1][j], 0, 0, 0);
                }
            }
            __syncthreads();
        }
#pragma unroll
        for (int i = 0; i < 2; ++i)
#pragma unroll
            for (int j = 0; j < 4; ++j)
#pragma unroll
                for (int r = 0; r < 4; ++r) {
                    int ir = (dv & 2) ? (4*r + (lane >> 4)) : (4*(lane >> 4) + r);
                    int ic = lane & 15;
                    if (dv & 1) { int t = ir; ir = ic; ic = t; }
                    int row = m0 + wm*32 + i*16 + ir;
                    int col = n0 + wn*64 + j*16 + ic;
                    if (row < M && col < N)
                        C[(size_t)row*N + col] = fa[i][j][r] + (bias ? (double)bias[col] : 0.0);
                }
        return;
    }

    // ---- SIMT fallback: two 64-col halves of the proven loop (dead path) --
    const int tx = tid & 15, ty = tid >> 4;
    for (int nh = 0; nh < 2; ++nh) {
        double acc[4][4] = {};
        for (int kt = 0; kt < K; kt += 16) {
            {
                double v[4];
                load_a4d<AMODE>(A, m0+lr, kt+lc, M, v);
                As[lr][lc+0]=v[0]; As[lr][lc+1]=v[1]; As[lr][lc+2]=v[2]; As[lr][lc+3]=v[3];
            }
            {
                double wv[4];
                load_w4d<WMODE>(W, n0 + nh*64 + lr, kt+lc, N, K, wv);
                Ws[lr][lc+0]=wv[0]; Ws[lr][lc+1]=wv[1]; Ws[lr][lc+2]=wv[2]; Ws[lr][lc+3]=wv[3];
            }
            __syncthreads();
#pragma unroll
            for (int k = 0; k < 16; ++k) {
                double a[4], b[4];
#pragma unroll
                for (int e = 0; e < 4; ++e) { a[e] = As[ty + 16*e][k]; b[e] = Ws[tx + 16*e][k]; }
#pragma unroll
                for (int i = 0; i < 4; ++i)
#pragma unroll
                    for (int j = 0; j < 4; ++j) acc[i][j] += a[i]*b[j];
            }
            __syncthreads();
        }
#pragma unroll
        for (int i = 0; i < 4; ++i) {
            int row = m0 + ty + 16*i;
            if (row >= M) continue;
#pragma unroll
            for (int j = 0; j < 4; ++j) {
                int col = n0 + nh*64 + tx + 16*j;
                if (col >= N) continue;
                C[(size_t)row*N + col] = acc[i][j] + (bias ? (double)bias[col] : 0.0);
            }
        }
        __syncthreads();
    }
}

// ---------------- int8 MFMA GEMM (exact), BK=128, XCD swizzle --------------
template<int GATE, int PRE>
__global__ __launch_bounds__(256)
void k_qgemm(const signed char* __restrict__ A8, const double* __restrict__ ascale,
             const float* __restrict__ Wf, const signed char* __restrict__ W8,
             const double* __restrict__ wsum, long long wcount,
             const float* __restrict__ bias, double* __restrict__ C,
             int M, int N, int K, int accum, int gridM)
{
    __shared__ __align__(16) signed char Als[8][128][16];
    __shared__ __align__(16) signed char Bls[8][128][16];
    __shared__ __align__(16) signed char B2ls[GATE?8:1][GATE?128:1][16];
    const int tid = threadIdx.x;
    const int lane = tid & 63, wid = tid >> 6;
    const int wr = wid >> 1, wc = wid & 1;             // 2x2 waves, 64x64 each
    const int2 bxy = xcd_swz(gridM);
    const int m0 = bxy.x*128, n0 = bxy.y*128;
    const int ks = lane >> 4, fr = lane & 15;

    const double dqw = fmax(*wsum / (double)wcount, 1e-5);
    const double thr = 0.5 * dqw;

    i32x4 acc[4][4];
    i32x4 acc2[GATE?4:1][4];
#pragma unroll
    for (int i = 0; i < 4; ++i)
#pragma unroll
        for (int j = 0; j < 4; ++j) {
            acc[i][j] = i32x4{0,0,0,0};
            if constexpr (GATE) acc2[i][j] = i32x4{0,0,0,0};
        }

    for (int kt = 0; kt < K; kt += 128) {
#pragma unroll
        for (int c = 0; c < 4; ++c) {
            int idx = tid + c*256;
            int row = idx & 127, kslot = idx >> 7;
            i32x4 v = {0,0,0,0};
            if (m0 + row < M)
                v = *reinterpret_cast<const i32x4*>(A8 + (size_t)(m0+row)*K + kt + kslot*16);
            *reinterpret_cast<i32x4*>(&Als[kslot][row][0]) = v;
        }
#pragma unroll
        for (int c = 0; c < 4; ++c) {
            int idx = tid + c*256;
            int row = idx & 127, kslot = idx >> 7;
            i32x4 pv = {0,0,0,0};
            if (n0 + row < N) {
                if constexpr (PRE) {
                    pv = *reinterpret_cast<const i32x4*>(W8 + (size_t)(n0+row)*K + kt + kslot*16);
                } else {
                    const float* wp = Wf + (size_t)(n0+row)*K + kt + kslot*16;
#pragma unroll
                    for (int d = 0; d < 4; ++d) {
                        float4 wv = *reinterpret_cast<const float4*>(wp + d*4);
                        float we[4] = {wv.x, wv.y, wv.z, wv.w};
                        unsigned p = 0;
#pragma unroll
                        for (int e = 0; e < 4; ++e) {
                            double wd = (double)we[e];
                            int q = (wd > thr) - (wd < -thr);
                            p |= ((unsigned)(q & 255)) << (8*e);
                        }
                        pv[d] = (int)p;
                    }
                }
            }
            *reinterpret_cast<i32x4*>(&Bls[kslot][row][0]) = pv;
        }
        if constexpr (GATE) {
#pragma unroll
            for (int c = 0; c < 4; ++c) {
                int idx = tid + c*256;
                int row = idx & 127, kslot = idx >> 7;
                i32x4 pv = {0,0,0,0};
                if (n0 + row < N) {
                    if constexpr (PRE) {
                        pv = *reinterpret_cast<const i32x4*>(W8 + (size_t)(n0+row+N)*K + kt + kslot*16);
                    } else {
                        const float* wp = Wf + (size_t)(n0+row+N)*K + kt + kslot*16;
#pragma unroll
                        for (int d = 0; d < 4; ++d) {
                            float4 wv = *reinterpret_cast<const float4*>(wp + d*4);
                            float we[4] = {wv.x, wv.y, wv.z, wv.w};
                            unsigned p = 0;
#pragma unroll
                            for (int e = 0; e < 4; ++e) {
                                double wd = (double)we[e];
                                int q = (wd > thr) - (wd < -thr);
                                p |= ((unsigned)(q & 255)) << (8*e);
                            }
                            pv[d] = (int)p;
                        }
                    }
                }
                *reinterpret_cast<i32x4*>(&B2ls[kslot][row][0]) = pv;
            }
        }
        __syncthreads();
#pragma unroll
        for (int kk = 0; kk < 2; ++kk) {
            const int kb = kk*4 + ks;
            i32x4 a[4];
#pragma unroll
            for (int i = 0; i < 4; ++i)
                a[i] = *reinterpret_cast<const i32x4*>(&Als[kb][wr*64 + i*16 + fr][0]);
#pragma unroll
            for (int j = 0; j < 4; ++j) {
                i32x4 b = *reinterpret_cast<const i32x4*>(&Bls[kb][wc*64 + j*16 + fr][0]);
#pragma unroll
                for (int i = 0; i < 4; ++i)
                    acc[i][j] = __builtin_amdgcn_mfma_i32_16x16x64_i8(a[i], b, acc[i][j], 0, 0, 0);
                if constexpr (GATE) {
                    i32x4 b2 = *reinterpret_cast<const i32x4*>(&B2ls[kb][wc*64 + j*16 + fr][0]);
#pragma unroll
                    for (int i = 0; i < 4; ++i)
                        acc2[i][j] = __builtin_amdgcn_mfma_i32_16x16x64_i8(a[i], b2, acc2[i][j], 0, 0, 0);
                }
            }
        }
        __syncthreads();
    }

#pragma unroll
    for (int i = 0; i < 4; ++i) {
#pragma unroll
        for (int r = 0; r < 4; ++r) {
            int row = m0 + wr*64 + i*16 + (lane>>4)*4 + r;
            if (row >= M) continue;
            double mul = dqw / ascale[row];
#pragma unroll
            for (int j = 0; j < 4; ++j) {
                int col = n0 + wc*64 + j*16 + (lane & 15);
                if (col >= N) continue;
                size_t o = (size_t)row*N + col;
                if constexpr (GATE) {
                    double g = (double)acc[i][j][r] * mul;
                    double y = (double)acc2[i][j][r] * mul;
                    C[o] = g/(1.0+exp(-g)) * y;
                } else {
                    double v = (double)acc[i][j][r] * mul;
                    if (bias) v += (double)bias[col];
                    C[o] = accum ? C[o] + v : v;
                }
            }
        }
    }
}

// ---------------- fused f/i/g GEMM (3 groups, fallback helper) -------------
__global__ __launch_bounds__(256)
void k_qgemm3(const signed char* __restrict__ A8, const double* __restrict__ ascale,
              W3 w3, long long wcount, int M, int gridM)
{
    __shared__ __align__(16) signed char Als[8][128][16];
    __shared__ __align__(16) signed char Bls[8][128][16];
    const int tid = threadIdx.x;
    const int lane = tid & 63, wid = tid >> 6;
    const int wr = wid >> 1, wc = wid & 1;
    const int2 bxy = xcd_swz(gridM);
    const int m0 = bxy.x*128;
    const int yy = bxy.y;
    const int g = yy / 9, nt = yy - g*9;
    const int n0 = nt*128;
    const signed char* W8 = w3.w[g];
    double* C = w3.c[g];
    const int ks = lane >> 4, fr = lane & 15;

    const double dqw = fmax(*w3.sc[g] / (double)wcount, 1e-5);

    i32x4 acc[4][4];
#pragma unroll
    for (int i = 0; i < 4; ++i)
#pragma unroll
        for (int j = 0; j < 4; ++j) acc[i][j] = i32x4{0,0,0,0};

    for (int kt = 0; kt < 1152; kt += 128) {
#pragma unroll
        for (int c = 0; c < 4; ++c) {
            int idx = tid + c*256;
            int row = idx & 127, kslot = idx >> 7;
            i32x4 v = {0,0,0,0};
            if (m0 + row < M)
                v = *reinterpret_cast<const i32x4*>(A8 + (size_t)(m0+row)*1152 + kt + kslot*16);
            *reinterpret_cast<i32x4*>(&Als[kslot][row][0]) = v;
        }
#pragma unroll
        for (int c = 0; c < 4; ++c) {
            int idx = tid + c*256;
            int row = idx & 127, kslot = idx >> 7;
            i32x4 pv = *reinterpret_cast<const i32x4*>(W8 + (size_t)(n0+row)*1152 + kt + kslot*16);
            *reinterpret_cast<i32x4*>(&Bls[kslot][row][0]) = pv;
        }
        __syncthreads();
#pragma unroll
        for (int kk = 0; kk < 2; ++kk) {
            const int kb = kk*4 + ks;
            i32x4 a[4];
#pragma unroll
            for (int i = 0; i < 4; ++i)
                a[i] = *reinterpret_cast<const i32x4*>(&Als[kb][wr*64 + i*16 + fr][0]);
#pragma unroll
            for (int j = 0; j < 4; ++j) {
                i32x4 b = *reinterpret_cast<const i32x4*>(&Bls[kb][wc*64 + j*16 + fr][0]);
#pragma unroll
                for (int i = 0; i < 4; ++i)
                    acc[i][j] = __builtin_amdgcn_mfma_i32_16x16x64_i8(a[i], b, acc[i][j], 0, 0, 0);
            }
        }
        __syncthreads();
    }

    const int gm3 = g % 3;
#pragma unroll
    for (int i = 0; i < 4; ++i) {
#pragma unroll
        for (int r = 0; r < 4; ++r) {
            int row = m0 + wr*64 + i*16 + (lane>>4)*4 + r;
            if (row >= M) continue;
            double mul = dqw / ascale[row];
#pragma unroll
            for (int j = 0; j < 4; ++j) {
                int col = n0 + wc*64 + j*16 + (lane & 15);
                double v = (double)acc[i][j][r] * mul;
                if (gm3 == 0)      v = 1.0/(1.0+exp(-v));
                else if (gm3 == 1) v = v/(1.0+exp(-v));
                C[(size_t)row*1152 + col] = v;
            }
        }
    }
}

// ---------------- fused self+mv+ref projections (9 groups) -----------------
__global__ __launch_bounds__(256)
void k_qgemm9(const signed char* __restrict__ A8s, const double* __restrict__ ascs,
              const signed char* __restrict__ A8r, const double* __restrict__ ascr,
              W9 w9, long long wcount)
{
    __shared__ __align__(16) signed char Als[8][128][16];
    __shared__ __align__(16) signed char Bls[8][128][16];
    const int tid = threadIdx.x;
    const int lane = tid & 63, wid = tid >> 6;
    const int wr = wid >> 1, wc = wid & 1;
    const int lb = xcd_swz(1).y;
    int m0, g, nt;
    const signed char* A8;
    const double* ascale;
    if (lb < 864) {
        m0 = (lb % 16)*128;
        int yy = lb / 16;
        g = yy / 9; nt = yy - g*9;
        A8 = A8s; ascale = ascs;
    } else {
        int l2 = lb - 864;
        m0 = (l2 % 4)*128;
        int yy2 = l2 / 4;
        g = 6 + yy2 / 9; nt = yy2 % 9;
        A8 = A8r; ascale = ascr;
    }
    const int n0 = nt*128;
    const signed char* W8 = w9.w[g];
    double* C = w9.c[g];
    const int ks = lane >> 4, fr = lane & 15;

    const double dqw = fmax(*w9.sc[g] / (double)wcount, 1e-5);

    i32x4 acc[4][4];
#pragma unroll
    for (int i = 0; i < 4; ++i)
#pragma unroll
        for (int j = 0; j < 4; ++j) acc[i][j] = i32x4{0,0,0,0};

    for (int kt = 0; kt < 1152; kt += 128) {
#pragma unroll
        for (int c = 0; c < 4; ++c) {
            int idx = tid + c*256;
            int row = idx & 127, kslot = idx >> 7;
            i32x4 v = *reinterpret_cast<const i32x4*>(A8 + (size_t)(m0+row)*1152 + kt + kslot*16);
            *reinterpret_cast<i32x4*>(&Als[kslot][row][0]) = v;
        }
#pragma unroll
        for (int c = 0; c < 4; ++c) {
            int idx = tid + c*256;
            int row = idx & 127, kslot = idx >> 7;
            i32x4 pv = *reinterpret_cast<const i32x4*>(W8 + (size_t)(n0+row)*1152 + kt + kslot*16);
            *reinterpret_cast<i32x4*>(&Bls[kslot][row][0]) = pv;
        }
        __syncthreads();
#pragma unroll
        for (int kk = 0; kk < 2; ++kk) {
            const int kb = kk*4 + ks;
            i32x4 a[4];
#pragma unroll
            for (int i = 0; i < 4; ++i)
                a[i] = *reinterpret_cast<const i32x4*>(&Als[kb][wr*64 + i*16 + fr][0]);
#pragma unroll
            for (int j = 0; j < 4; ++j) {
                i32x4 b = *reinterpret_cast<const i32x4*>(&Bls[kb][wc*64 + j*16 + fr][0]);
#pragma unroll
                for (int i = 0; i < 4; ++i)
                    acc[i][j] = __builtin_amdgcn_mfma_i32_16x16x64_i8(a[i], b, acc[i][j], 0, 0, 0);
            }
        }
        __syncthreads();
    }

    const int gm3 = g % 3;    // 0=f->sigma, 1=i->silu, 2=g->raw
#pragma unroll
    for (int i = 0; i < 4; ++i) {
#pragma unroll
        for (int r = 0; r < 4; ++r) {
            int row = m0 + wr*64 + i*16 + (lane>>4)*4 + r;
            double mul = dqw / ascale[row];
#pragma unroll
            for (int j = 0; j < 4; ++j) {
                int col = n0 + wc*64 + j*16 + (lane & 15);
                double v = (double)acc[i][j][r] * mul;
                if (gm3 == 0)      v = 1.0/(1.0+exp(-v));
                else if (gm3 == 1) v = v/(1.0+exp(-v));
                C[(size_t)row*1152 + col] = v;
            }
        }
    }
}

// combined self+mv+ref o-projection.
__global__ __launch_bounds__(256)
void k_qgemmO3(const signed char* __restrict__ A8, const double* __restrict__ ascale,
               const signed char* __restrict__ Ws8, const signed char* __restrict__ Wm8,
               const signed char* __restrict__ Wr8,
               const double* __restrict__ scs, const double* __restrict__ scm,
               const double* __restrict__ scr, long long wcount,
               double* __restrict__ Cs, double* __restrict__ Cm, double* __restrict__ Cr)
{
    __shared__ __align__(16) signed char Als[8][128][16];
    __shared__ __align__(16) signed char Bls[8][128][16];
    const int tid = threadIdx.x;
    const int lane = tid & 63, wid = tid >> 6;
    const int wr = wid >> 1, wc = wid & 1;
    const int lb = xcd_swz(1).y;
    int m0, nt;
    const signed char* W8;
    const signed char* A;
    const double* as;
    double* C;
    double scv;
    if (lb < 144)      { m0 = (lb % 16)*128; nt = lb / 16; W8 = Ws8; A = A8;
                         as = ascale; C = Cs; scv = *scs; }
    else if (lb < 288) { int l2 = lb - 144; m0 = (l2 % 16)*128; nt = l2 / 16; W8 = Wm8;
                         A = A8 + (size_t)2048*1152; as = ascale + 2048; C = Cm; scv = *scm; }
    else               { int l3 = lb - 288; m0 = (l3 % 4)*128; nt = l3 / 4; W8 = Wr8;
                         A = A8 + (size_t)4096*1152; as = ascale + 4096; C = Cr; scv = *scr; }
    const int n0 = nt*128;
    const int ks = lane >> 4, fr = lane & 15;

    const double dqw = fmax(scv / (double)wcount, 1e-5);

    i32x4 acc[4][4];
#pragma unroll
    for (int i = 0; i < 4; ++i)
#pragma unroll
        for (int j = 0; j < 4; ++j) acc[i][j] = i32x4{0,0,0,0};

    for (int kt = 0; kt < 1152; kt += 128) {
#pragma unroll
        for (int c = 0; c < 4; ++c) {
            int idx = tid + c*256;
            int row = idx & 127, kslot = idx >> 7;
            i32x4 v = *reinterpret_cast<const i32x4*>(A + (size_t)(m0+row)*1152 + kt + kslot*16);
            *reinterpret_cast<i32x4*>(&Als[kslot][row][0]) = v;
        }
#pragma unroll
        for (int c = 0; c < 4; ++c) {
            int idx = tid + c*256;
            int row = idx & 127, kslot = idx >> 7;
            i32x4 pv = *reinterpret_cast<const i32x4*>(W8 + (size_t)(n0+row)*1152 + kt + kslot*16);
            *reinterpret_cast<i32x4*>(&Bls[kslot][row][0]) = pv;
        }
        __syncthreads();
#pragma unroll
        for (int kk = 0; kk < 2; ++kk) {
            const int kb = kk*4 + ks;
            i32x4 a[4];
#pragma unroll
            for (int i = 0; i < 4; ++i)
                a[i] = *reinterpret_cast<const i32x4*>(&Als[kb][wr*64 + i*16 + fr][0]);
#pragma unroll
            for (int j = 0; j < 4; ++j) {
                i32x4 b = *reinterpret_cast<const i32x4*>(&Bls[kb][wc*64 + j*16 + fr][0]);
#pragma unroll
                for (int i = 0; i < 4; ++i)
                    acc[i][j] = __builtin_amdgcn_mfma_i32_16x16x64_i8(a[i], b, acc[i][j], 0, 0, 0);
            }
        }
        __syncthreads();
    }

#pragma unroll
    for (int i = 0; i < 4; ++i) {
#pragma unroll
        for (int r = 0; r < 4; ++r) {
            int row = m0 + wr*64 + i*16 + (lane>>4)*4 + r;
            double mul = dqw / as[row];
#pragma unroll
            for (int j = 0; j < 4; ++j) {
                int col = n0 + wc*64 + j*16 + (lane & 15);
                C[(size_t)row*1152 + col] = (double)acc[i][j][r] * mul;
            }
        }
    }
}

// ---------------------------------------------------------------------------
extern "C" void kernel_launch(void* const* d_in, const int* in_sizes, int n_in,
                              void* d_out, int out_size, void* d_ws, size_t ws_size,
                              hipStream_t stream)
{
    (void)in_sizes; (void)n_in; (void)out_size;
    auto in = [&](int i){ return (const float*)d_in[i]; };

    const float *X = in(0), *T = in(1), *Y = in(2), *XC = in(3), *REF = in(4);
    const float *xe_w = in(6), *xe_b = in(7), *pos = in(8);
    const float *te_w1 = in(9), *te_b1 = in(10), *te_w2 = in(11), *te_b2 = in(12);
    const float *pp_w = in(13), *pp_b = in(14);
    const float *sa_pe_w = in(15), *sa_pe_b = in(16);
    const float *sa_ln_g = in(17), *sa_ln_b = in(18);
    const float *sa_gate_w = in(19), *sa_down_w = in(20);
    const float *sa_dc_w = in(21), *sa_dc_b = in(22);
    const float *ada_w = in(23), *ada_b = in(24);
    const float *sa_wi = in(25), *sa_wf = in(26), *sa_wg = in(27), *sa_wo = in(28);
    const float *mv_wi = in(29), *mv_wf = in(30), *mv_wg = in(31), *mv_wo = in(32);
    const float *rf_wi = in(33), *rf_wf = in(34), *rf_wg = in(35), *rf_wo = in(36);
    const float *gate_w = in(37), *down_w = in(38);
    const float *fl_w = in(39), *fl_b = in(40), *fl_ada_w = in(41), *fl_ada_b = in(42);
    float* OUT = (float*)d_out;

    // ---------- workspace layout ----------
    size_t off = 0;
    auto AL = [&](size_t bytes){ off = (off+255)&~(size_t)255; size_t r = off; off += bytes; return r; };
    const size_t oScale = AL(37*8);
    const size_t oPart  = AL(37*32*8);
    const size_t oProbe = AL(64*4*8);
    const size_t oFlag  = AL(256);
    const size_t oSM1 = AL(8*1152*8), oSM2 = AL(8*1152*8), oSM3 = AL(8*1152*8);
    const size_t oCB  = AL(8*1152*8);
    const size_t oMOD = AL(8*6912*8);
    const size_t oH   = AL((size_t)8192*1152*8);    // 75.5 MB; OB_self/OB_mv/OB_ref
    const size_t oINT = AL((size_t)1024*4608*8);    // 37.7 MB; FB2/IB2/MVB later
    const size_t oF0  = AL((size_t)2048*1152*8);    // also ACC
    const size_t oXT  = AL((size_t)2048*1152*8);
    const size_t oFB  = AL((size_t)2048*1152*8);
    const size_t oIB  = AL((size_t)2048*1152*8);
    const size_t oGB  = AL((size_t)2048*1152*8);
    const size_t oGB2 = AL((size_t)2048*1152*8);    // mv g (fused path)
    const size_t oFBr = AL((size_t)512*1152*8);     // ref f (fused path)
    const size_t oIBr = AL((size_t)512*1152*8);     // ref i
    const size_t oGBr = AL((size_t)512*1152*8);     // ref g
    const size_t oRO  = AL((size_t)512*1152*8);
    const size_t oQ8X = AL((size_t)2048*1152);
    const size_t oQ8I = AL((size_t)1024*4608);
    const size_t oQ8O = AL((size_t)2048*1152);
    const size_t oQ8O2= AL((size_t)4608*1152);      // fused self+mv+ref ogate out
    const size_t oQ8R = AL((size_t)512*1152);
    const size_t oQ8T = AL((size_t)8*1152);
    const size_t oQ8C = AL((size_t)8*1152);
    const size_t oDSX = AL(2048*8), oDSI = AL(1024*8), oDSO = AL(2048*8);
    const size_t oDSO2= AL(4608*8);
    const size_t oDSR = AL(512*8),  oDST = AL(8*8),    oDSC = AL(8*8);
    if (off > ws_size) return;

    // ---------- weight list + optional pre-ternarized region ----------
    WList wl{}; WOffs wo{};
    long long wn[37];
    int nw = 0;
    auto addw = [&](const float* w, long long n){ wl.p[nw]=w; wl.n[nw]=n; wn[nw]=n; nw++; };
    addw(te_w1, 294912); addw(te_w2, 1327104); addw(pp_w, 884736);
    addw(sa_gate_w, 10616832); addw(sa_down_w, 5308416);
    for (int l = 0; l < 2; ++l) {
        addw(ada_w + (size_t)l*7962624, 7962624);
        addw(sa_wi + (size_t)l*1327104, 1327104);
        addw(sa_wf + (size_t)l*1327104, 1327104);
        addw(sa_wg + (size_t)l*1327104, 1327104);
        addw(sa_wo + (size_t)l*1327104, 1327104);
        addw(mv_wi + (size_t)l*1327104, 1327104);
        addw(mv_wf + (size_t)l*1327104, 1327104);
        addw(mv_wg + (size_t)l*1327104, 1327104);
        addw(mv_wo + (size_t)l*1327104, 1327104);
        addw(rf_wi + (size_t)l*1327104, 1327104);
        addw(rf_wf + (size_t)l*1327104, 1327104);
        addw(rf_wg + (size_t)l*1327104, 1327104);
        addw(rf_wo + (size_t)l*1327104, 1327104);
        addw(gate_w + (size_t)l*10616832, 10616832);
        addw(down_w + (size_t)l*5308416, 5308416);
    }
    addw(fl_ada_w, 2654208); addw(fl_w, 36864);

    size_t off_saved = off;
    long long wtot = 0;
    for (int i = 0; i < 37; ++i) { wo.o[i] = wtot; wtot += (wn[i] + 255) & ~255LL; }
    const size_t oW8 = AL((size_t)wtot);
    const bool useW8 = (off <= ws_size);
    if (!useW8) off = off_saved;

    // ---------- optional transposed down-conv weight (f32, 21 MB) ----------
    size_t off_wt = off;
    const size_t oWt = AL((size_t)1152*4608*4);
    const bool useWt = (off <= ws_size);
    if (!useWt) off = off_wt;

    // ---------- tiered SA/MLP chunk enlargement (row-independent) ----------
    int schunk = 1024;
    size_t oINTb = 0, oQ8Ib = 0, oQ8Xb = 0, oDSXb = 0, oDSIb = 0;
    if (useW8) {
        size_t off_w8 = off;
        oINTb = AL((size_t)4096*4608*8); oQ8Ib = AL((size_t)4096*4608);
        oQ8Xb = AL((size_t)4096*1152);   oDSXb = AL(4096*8); oDSIb = AL(4096*8);
        if (off <= ws_size) schunk = 4096;
        else {
            off = off_w8;
            oINTb = AL((size_t)2048*4608*8); oQ8Ib = AL((size_t)2048*4608); oDSIb = AL(2048*8);
            if (off <= ws_size) schunk = 2048;
            else off = off_w8;
        }
    }

    char* w8p = (char*)d_ws;
    double* scales = (double*)(w8p + oScale);
    double* parts  = (double*)(w8p + oPart);
    double* probeD = (double*)(w8p + oProbe);
    int*    mflag  = (int*)(w8p + oFlag);
    double *SM1=(double*)(w8p+oSM1), *SM2=(double*)(w8p+oSM2), *SM3=(double*)(w8p+oSM3);
    double *CB=(double*)(w8p+oCB), *MOD=(double*)(w8p+oMOD);
    double *H=(double*)(w8p+oH), *INT=(double*)(w8p+oINT);
    double *F0=(double*)(w8p+oF0), *XT=(double*)(w8p+oXT);
    double *FB=(double*)(w8p+oFB), *IB=(double*)(w8p+oIB), *GB=(double*)(w8p+oGB);
    double *GB2=(double*)(w8p+oGB2);
    double *FBr=(double*)(w8p+oFBr), *IBr=(double*)(w8p+oIBr), *GBr=(double*)(w8p+oGBr);
    double *ACC=F0, *OB=H, *RO=(double*)(w8p+oRO);
    double *FB2 = INT, *IB2 = INT + (size_t)2048*1152;          // base INT reuse
    double *MVB = FB2;                                          // free after scans
    double *OBs = OB, *OBm = OB + (size_t)2048*1152;
    double *OBr = OB + (size_t)4096*1152;
    signed char *Q8X=(signed char*)(w8p+oQ8X), *Q8I=(signed char*)(w8p+oQ8I);
    signed char *Q8O=(signed char*)(w8p+oQ8O), *Q8O2=(signed char*)(w8p+oQ8O2);
    signed char *Q8R=(signed char*)(w8p+oQ8R);
    signed char *Q8T=(signed char*)(w8p+oQ8T), *Q8C=(signed char*)(w8p+oQ8C);
    double *DSX=(double*)(w8p+oDSX), *DSI=(double*)(w8p+oDSI), *DSO=(double*)(w8p+oDSO);
    double *DSO2=(double*)(w8p+oDSO2);
    double *DSR=(double*)(w8p+oDSR), *DST=(double*)(w8p+oDST), *DSC=(double*)(w8p+oDSC);
    signed char* W8 = (signed char*)(w8p + oW8);
    float* Wt = (float*)(w8p + oWt);

    double*      INTs = (schunk > 1024) ? (double*)(w8p + oINTb) : INT;
    signed char* Q8Is = (schunk > 1024) ? (signed char*)(w8p + oQ8Ib) : Q8I;
    double*      DSIs = (schunk > 1024) ? (double*)(w8p + oDSIb) : DSI;
    signed char* Q8Xs = (schunk == 4096) ? (signed char*)(w8p + oQ8Xb) : Q8X;
    double*      DSXs = (schunk == 4096) ? (double*)(w8p + oDSXb) : DSX;

    // ---------- probe + scales + ternarize + dc-w transpose ----------
    k_mfma64_probe<<<1, 64, 0, stream>>>(probeD);
    k_mfma64_check<<<1, 64, 0, stream>>>(probeD, mflag);
    k_abssum_all<<<dim3(32,37), 256, 0, stream>>>(wl, parts);
    k_abssum_fin<<<37, 64, 0, stream>>>(parts, scales);
    if (useW8)
        k_ternarize<<<dim3(64,37), 256, 0, stream>>>(wl, wo, scales, W8);
    if (useWt)
        k_dcw_prep<<<1152, 256, 0, stream>>>(sa_dc_w, Wt);

    // ---------- launch helpers ----------
    auto qgemm = [&](const signed char* A8, const double* as, const float* Win, int slot,
                     const float* b, double* Cout, int M, int N, int K, int accum){
        int gm = (M+127)/128, gn = (N+127)/128;
        if (useW8)
            k_qgemm<0,1><<<gm*gn, 256, 0, stream>>>(A8, as, Win, W8 + wo.o[slot],
                                                    scales+slot, wn[slot], b, Cout, M, N, K, accum, gm);
        else
            k_qgemm<0,0><<<gm*gn, 256, 0, stream>>>(A8, as, Win, nullptr,
                                                    scales+slot, wn[slot], b, Cout, M, N, K, accum, gm);
    };
    auto qgemmGate = [&](const signed char* A8, const double* as, const float* Win, int slot,
                         double* Cout, int M){
        int gm = (M+127)/128;
        if (useW8)
            k_qgemm<1,1><<<gm*36, 256, 0, stream>>>(A8, as, Win, W8 + wo.o[slot],
                                                    scales+slot, wn[slot], nullptr, Cout, M, 4608, 1152, 0, gm);
        else
            k_qgemm<1,0><<<gm*36, 256, 0, stream>>>(A8, as, Win, nullptr,
                                                    scales+slot, wn[slot], nullptr, Cout, M, 4608, 1152, 0, gm);
    };
    auto fig = [&](const signed char* A8, const double* as, int sF, int sI, int sG,
                   const float* wF, const float* wI, const float* wG, int M,
                   int n_outer, long long ostr, int n_inner, long long tstr, int Tlen){
        if (useW8) {
            W3 w3{ {W8+wo.o[sF], W8+wo.o[sI], W8+wo.o[sG]},
                   {scales+sF, scales+sI, scales+sG},
                   {FB, IB, GB} };
            int gm = M/128;
            k_qgemm3<<<gm*27, 256, 0, stream>>>(A8, as, w3, 1327104, M, gm);
            long long nch = (long long)n_outer*n_inner;
            k_scan3<<<(unsigned)((nch+255)/256), 256, 0, stream>>>(FB, IB, OB, n_outer, ostr, n_inner, tstr, Tlen);
        } else {
            qgemm(A8, as, wF, sF, nullptr, FB, M, 1152, 1152, 0);
            qgemm(A8, as, wI, sI, nullptr, IB, M, 1152, 1152, 0);
            qgemm(A8, as, wG, sG, nullptr, GB, M, 1152, 1152, 0);
            long long nel = (long long)M*1152;
            k_gatepre<<<(unsigned)((nel+255)/256), 256, 0, stream>>>(FB, IB, nel);
            long long nch = (long long)n_outer*n_inner;
            k_scan2<<<(unsigned)((nch+255)/256), 256, 0, stream>>>(FB, IB, OB, n_outer, ostr, n_inner, tstr, Tlen);
        }
    };
    auto rsq8big = [&](const double* xi, signed char* q8, double* ds, int M){
        if (useW8) k_rsq8c<<<M, 256, 4608*8, stream>>>(xi, q8, ds, 4608);
        else       k_rsq8<double><<<M, 256, 0, stream>>>(xi, q8, ds, 4608, 0);
    };

    // ---------- conditioning vector c ----------
    k_temb<<<8, 128, 0, stream>>>(T, SM1);
    k_rsq8<double><<<8, 256, 0, stream>>>(SM1, Q8T, DST, 256, 0);
    qgemm(Q8T, DST, te_w1, 0, te_b1, SM3, 8, 1152, 256, 0);
    k_rsq8<double><<<8, 256, 0, stream>>>(SM3, Q8T, DST, 1152, 1);
    qgemm(Q8T, DST, te_w2, 1, te_b2, SM2, 8, 1152, 1152, 0);
    k_rsq8<float><<<8, 256, 0, stream>>>(Y, Q8T, DST, 768, 0);
    qgemm(Q8T, DST, pp_w, 2, pp_b, SM3, 8, 1152, 768, 0);
    k_add<<<36, 256, 0, stream>>>(SM2, SM3, CB, 9216);
    k_rsq8<double><<<8, 256, 0, stream>>>(CB, Q8C, DSC, 1152, 1);

    // ---------- spatial adapter: patch embed + block 0 only ----------
    k_dgemm<1,0><<<9*128, 256, 0, stream>>>(XC, sa_pe_w, sa_pe_b, H, 8192, 1152, 1536, 9, mflag);
    {
        const int nch = 8192 / schunk;
        for (int ch = 0; ch < nch; ++ch) {
            double* Hrow = H + (size_t)ch*schunk*1152;
            k_lnq8<<<schunk, 256, 1152*8, stream>>>(Hrow, Q8Xs, DSXs, 1152, sa_ln_g, sa_ln_b,
                                                    nullptr, nullptr, 0, 1e-5);
            qgemmGate(Q8Xs, DSXs, sa_gate_w, 3, INTs, schunk);
            rsq8big(INTs, Q8Is, DSIs, schunk);
            qgemm(Q8Is, DSIs, sa_down_w, 4, nullptr, Hrow, schunk, 1152, 4608, 0);
        }
    }
    if (useWt)
        k_dgemm<2,0><<<9*32, 256, 0, stream>>>(H, Wt, sa_dc_b, F0, 2048, 1152, 4608, 9, mflag);
    else
        k_dgemm<2,1><<<9*32, 256, 0, stream>>>(H, sa_dc_w, sa_dc_b, F0, 2048, 1152, 4608, 9, mflag);

    // ---------- patchify latents + pos + feats0 ----------
    k_patchify<<<9216, 256, 0, stream>>>(X, xe_w, xe_b, pos, F0, XT);
    k_rsq8<float><<<512, 256, 0, stream>>>(REF, Q8R, DSR, 1152, 0);

    // ---------- transformer blocks ----------
    for (int l = 0; l < 2; ++l) {
        int sb = 5 + l*15;
        const float *wada = ada_w + (size_t)l*7962624, *bada = ada_b + (size_t)l*6912;
        const float *swi = sa_wi + (size_t)l*1327104, *swf = sa_wf + (size_t)l*1327104;
        const float *swg = sa_wg + (size_t)l*1327104, *swo = sa_wo + (size_t)l*1327104;
        const float *mwi = mv_wi + (size_t)l*1327104, *mwf = mv_wf + (size_t)l*1327104;
        const float *mwg = mv_wg + (size_t)l*1327104, *mwo = mv_wo + (size_t)l*1327104;
        const float *rwi = rf_wi + (size_t)l*1327104, *rwf = rf_wf + (size_t)l*1327104;
        const float *rwg = rf_wg + (size_t)l*1327104, *rwo = rf_wo + (size_t)l*1327104;
        const float *wgt = gate_w + (size_t)l*10616832, *wdn = down_w + (size_t)l*5308416;

        qgemm(Q8C, DSC, wada, sb+0, bada, MOD, 8, 6912, 1152, 0);

        k_lnq8<<<2048, 256, 1152*8, stream>>>(XT, Q8X, DSX, 1152, nullptr, nullptr,
                                              MOD+0, MOD+1152, 6912, 1e-6);

        if (useW8) {
            // ---- fused self+mv+ref attention ----
            W9 w9{ {W8+wo.o[sb+2], W8+wo.o[sb+1], W8+wo.o[sb+3],
                    W8+wo.o[sb+6], W8+wo.o[sb+5], W8+wo.o[sb+7],
                    W8+wo.o[sb+10], W8+wo.o[sb+9], W8+wo.o[sb+11]},
                   {scales+sb+2, scales+sb+1, scales+sb+3,
                    scales+sb+6, scales+sb+5, scales+sb+7,
                    scales+sb+10, scales+sb+9, scales+sb+11},
                   {FB, IB, GB, FB2, IB2, GB2, FBr, IBr, GBr} };
            k_qgemm9<<<972, 256, 0, stream>>>(Q8X, DSX, Q8R, DSR, w9, 1327104);
            k_scanc3<<<(9216 + 589824 + 2304 + 255)/256, 256, 0, stream>>>(
                FB, IB, FB2, IB2, FBr, IBr, OBs, OBm, OBr);
            k_ogateq8c3<<<4608, 256, 1152*8, stream>>>(OBs, GB, OBm, GB2, OBr, GBr, Q8O2, DSO2);
            k_qgemmO3<<<324, 256, 0, stream>>>(Q8O2, DSO2,
                                               W8+wo.o[sb+4], W8+wo.o[sb+8], W8+wo.o[sb+12],
                                               scales+sb+4, scales+sb+8, scales+sb+12,
                                               1327104, ACC, MVB, RO);
            k_resid_attn2<<<9216, 256, 0, stream>>>(XT, ACC, MVB, RO, MOD);
        } else {
            // ---- proven sequential path ----
            fig(Q8X, DSX, sb+2, sb+1, sb+3, swf, swi, swg, 2048, 8, 294912LL, 1152, 1152LL, 256);
            k_ogateq8<<<2048, 256, 1152*8, stream>>>(OB, GB, Q8O, DSO, 1152);
            qgemm(Q8O, DSO, swo, sb+4, nullptr, ACC, 2048, 1152, 1152, 0);
            fig(Q8X, DSX, sb+6, sb+5, sb+7, mwf, mwi, mwg, 2048, 2, 1179648LL, 294912, 294912LL, 4);
            k_ogateq8<<<2048, 256, 1152*8, stream>>>(OB, GB, Q8O, DSO, 1152);
            qgemm(Q8O, DSO, mwo, sb+8, nullptr, ACC, 2048, 1152, 1152, 1);
            fig(Q8R, DSR, sb+10, sb+9, sb+11, rwf, rwi, rwg, 512, 2, 294912LL, 1152, 1152LL, 256);
            k_ogateq8<<<512, 256, 1152*8, stream>>>(OB, GB, Q8O, DSO, 1152);
            qgemm(Q8O, DSO, rwo, sb+12, nullptr, RO, 512, 1152, 1152, 0);
            k_resid_attn<<<9216, 256, 0, stream>>>(XT, ACC, RO, MOD);
        }

        // MLP
        k_lnq8<<<2048, 256, 1152*8, stream>>>(XT, Q8X, DSX, 1152, nullptr, nullptr,
                                              MOD+3*1152, MOD+4*1152, 6912, 1e-6);
        if (schunk >= 2048) {
            qgemmGate(Q8X, DSX, wgt, sb+13, INTs, 2048);
            rsq8big(INTs, Q8Is, DSIs, 2048);
            qgemm(Q8Is, DSIs, wdn, sb+14, nullptr, OB, 2048, 1152, 4608, 0);
        } else {
            for (int ch = 0; ch < 2; ++ch) {
                qgemmGate(Q8X + (size_t)ch*1024*1152, DSX + ch*1024, wgt, sb+13, INT, 1024);
                k_rsq8<double><<<1024, 256, 0, stream>>>(INT, Q8I, DSI, 4608, 0);
                qgemm(Q8I, DSI, wdn, sb+14, nullptr, OB + (size_t)ch*1024*1152, 1024, 1152, 4608, 0);
            }
        }
        k_resid_mlp<<<9216, 256, 0, stream>>>(XT, OB, MOD);
    }

    // ---------- final layer + unpatchify ----------
    qgemm(Q8C, DSC, fl_ada_w, 35, fl_ada_b, MOD, 8, 2304, 1152, 0);
    k_lnq8<<<2048, 256, 1152*8, stream>>>(XT, Q8X, DSX, 1152, nullptr, nullptr,
                                          MOD+0, MOD+1152, 2304, 1e-6);
    qgemm(Q8X, DSX, fl_w, 36, fl_b, FB, 2048, 32, 1152, 0);
    k_unpatch<<<256, 256, 0, stream>>>(FB, OUT);
}

// Round 18
// 4211.539 us; speedup vs baseline: 1.1387x; 1.1387x over previous
//
#include <hip/hip_runtime.h>

#define DEV __device__ __forceinline__

typedef __attribute__((ext_vector_type(4))) int i32x4;
typedef __attribute__((ext_vector_type(4))) double f64x4;

// ---------------------------------------------------------------------------
// TernaryMVAdapter forward on MI355X. Round 18: REVERT to the round-16 proven
// configuration (4212us). Round 17's 64x128/BK=16/prefetch dgemm regressed
// (occupancy 34->10%, 606->901us) — second independent failure of the 64x128
// tile; the 64x64/BK=32 MFMA dgemm is the empirical optimum of this family.
// ---------------------------------------------------------------------------

struct WList { const float* p[37]; long long n[37]; };
struct WOffs { long long o[37]; };
struct W3 { const signed char* w[3]; const double* sc[3]; double* c[3]; };
struct W9 { const signed char* w[9]; const double* sc[9]; double* c[9]; };

DEV int2 xcd_swz(int gridx)
{
    const int nwg = (int)gridDim.x, b = (int)blockIdx.x;
    const int q = nwg >> 3, r = nwg & 7, xcd = b & 7, idx = b >> 3;
    const int lb = (xcd < r ? xcd*(q+1) : r*(q+1) + (xcd-r)*q) + idx;
    return make_int2(lb % gridx, lb / gridx);
}

// ---------------- f64 MFMA layout probe (exact-integer classification) -----
__global__ void k_mfma64_probe(double* __restrict__ out)
{
    const int lane = threadIdx.x;                      // 64 threads
    double a = (double)(1 + lane);
    double b = (double)(101 + 3*lane);
    f64x4 acc = {0.0, 0.0, 0.0, 0.0};
    acc = __builtin_amdgcn_mfma_f64_16x16x4f64(a, b, acc, 0, 0, 0);
#pragma unroll
    for (int r = 0; r < 4; ++r) out[lane*4 + r] = acc[r];
}

__global__ void k_mfma64_check(const double* __restrict__ probe, int* __restrict__ flag)
{
    if (threadIdx.x != 0) return;
    int best = 0;
    for (int c = 0; c < 16 && !best; ++c) {
        const int a_alt = c & 1, b_alt = (c >> 1) & 1, dv = (c >> 2) & 3;
        double Amat[16][4], Bmat[4][16];
        for (int l = 0; l < 64; ++l) {
            int ai = a_alt ? (l >> 2) : (l & 15);
            int ak = a_alt ? (l & 3)  : (l >> 4);
            Amat[ai][ak] = (double)(1 + l);
            int bj = b_alt ? (l >> 2) : (l & 15);
            int bk = b_alt ? (l & 3)  : (l >> 4);
            Bmat[bk][bj] = (double)(101 + 3*l);
        }
        double C[16][16];
        for (int i = 0; i < 16; ++i)
            for (int j = 0; j < 16; ++j) {
                double s = 0.0;
                for (int k = 0; k < 4; ++k) s += Amat[i][k] * Bmat[k][j];
                C[i][j] = s;
            }
        bool ok = true;
        for (int l = 0; l < 64 && ok; ++l)
            for (int r = 0; r < 4 && ok; ++r) {
                int ir = (dv & 2) ? (4*r + (l >> 4)) : (4*(l >> 4) + r);
                int ic = l & 15;
                if (dv & 1) { int t = ir; ir = ic; ic = t; }
                if (probe[l*4 + r] != C[ir][ic]) ok = false;
            }
        if (ok) best = 1 + c;
    }
    *flag = best;
}

// ---------------- fused deterministic |w| sums (37 slots) ------------------
__global__ void k_abssum_all(WList wl, double* __restrict__ partials)
{
    const int slot = blockIdx.y;
    const float* w = wl.p[slot];
    const long long n = wl.n[slot];
    __shared__ double sm[256];
    double s = 0.0;
    for (long long i = (long long)blockIdx.x*256 + threadIdx.x; i < n; i += 32LL*256)
        s += (double)fabsf(w[i]);
    sm[threadIdx.x] = s;
    __syncthreads();
    for (int k = 128; k > 0; k >>= 1) {
        if ((int)threadIdx.x < k) sm[threadIdx.x] += sm[threadIdx.x + k];
        __syncthreads();
    }
    if (threadIdx.x == 0) partials[slot*32 + blockIdx.x] = sm[0];
}

__global__ void k_abssum_fin(const double* __restrict__ partials, double* __restrict__ out)
{
    const int slot = blockIdx.x;
    if (threadIdx.x == 0) {
        double s = 0.0;
        for (int i = 0; i < 32; ++i) s += partials[slot*32 + i];
        out[slot] = s;
    }
}

// ---------------- one-time weight ternarization (f64-exact decision) -------
__global__ void k_ternarize(WList wl, WOffs wo, const double* __restrict__ scales,
                            signed char* __restrict__ W8)
{
    const int slot = blockIdx.y;
    const float* w = wl.p[slot];
    const long long n4 = wl.n[slot] >> 2;
    const double dqw = fmax(scales[slot] / (double)wl.n[slot], 1e-5);
    const double thr = 0.5 * dqw;
    signed char* o = W8 + wo.o[slot];
    for (long long i = (long long)blockIdx.x*256 + threadIdx.x; i < n4; i += 64LL*256) {
        float4 v = *reinterpret_cast<const float4*>(w + i*4);
        float we[4] = {v.x, v.y, v.z, v.w};
        char r[4];
#pragma unroll
        for (int e = 0; e < 4; ++e) {
            double wd = (double)we[e];
            r[e] = (char)((wd > thr) - (wd < -thr));
        }
        *reinterpret_cast<char4*>(o + i*4) = make_char4(r[0], r[1], r[2], r[3]);
    }
}

// ---------------- sa_dc_w pre-transpose to linear k' -----------------------
__global__ void k_dcw_prep(const float* __restrict__ w, float* __restrict__ wt)
{
    int row = blockIdx.x;                              // 1152
    for (int k = threadIdx.x; k < 4608; k += 256) {
        int q = k / 1152, c = k - q*1152;
        wt[(size_t)row*4608 + k] = w[(size_t)row*4608 + (size_t)c*4 + q];
    }
}

// ---------------- timestep frequency embedding (f64) -----------------------
__global__ void k_temb(const float* __restrict__ t, double* __restrict__ out)
{
    int b = blockIdx.x, j = threadIdx.x;               // 8 x 128
    double fr  = exp(-9.210340371976184 * (double)j / 128.0);
    double ang = (double)t[b] * fr;
    out[b*256 + j]       = cos(ang);
    out[b*256 + 128 + j] = sin(ang);
}

// ---------------- rmsnorm + int8 absmax quant (f64, LDS-free) --------------
template<typename TI>
__global__ void k_rsq8(const TI* __restrict__ x, signed char* __restrict__ q8,
                       double* __restrict__ dscale, int K, int pre_silu)
{
    __shared__ double red[256], red2[256];
    const int row = blockIdx.x, tid = threadIdx.x;
    const TI* xr = x + (size_t)row*K;
    double ss = 0.0, am = 0.0;
    for (int i = tid; i < K; i += 256) {
        double v = (double)xr[i];
        if (pre_silu) v = v / (1.0 + exp(-v));
        ss += v*v; am = fmax(am, fabs(v));
    }
    red[tid] = ss; red2[tid] = am;
    __syncthreads();
    for (int s = 128; s > 0; s >>= 1) {
        if (tid < s) { red[tid] += red[tid+s]; red2[tid] = fmax(red2[tid], red2[tid+s]); }
        __syncthreads();
    }
    double rms = 1.0 / sqrt(red[0]/(double)K + 1e-8);
    double s   = 127.0 / fmax(red2[0]*rms, 1e-5);
    signed char* orow = q8 + (size_t)row*K;
    for (int i = tid; i < K; i += 256) {
        double v = (double)xr[i];
        if (pre_silu) v = v / (1.0 + exp(-v));
        orow[i] = (signed char)(int)fmin(fmax(rint(v*rms*s), -128.0), 127.0);
    }
    if (tid == 0) dscale[row] = s;
}

// LDS-cached single-read variant (for K=4608: avoids 2nd 151MB HBM pass)
__global__ void k_rsq8c(const double* __restrict__ x, signed char* __restrict__ q8,
                        double* __restrict__ dscale, int K)
{
    extern __shared__ double rb[];
    __shared__ double red[256], red2[256];
    const int row = blockIdx.x, tid = threadIdx.x;
    const double* xr = x + (size_t)row*K;
    double ss = 0.0, am = 0.0;
    for (int i = tid; i < K; i += 256) {
        double v = xr[i];
        rb[i] = v; ss += v*v; am = fmax(am, fabs(v));
    }
    red[tid] = ss; red2[tid] = am;
    __syncthreads();
    for (int s = 128; s > 0; s >>= 1) {
        if (tid < s) { red[tid] += red[tid+s]; red2[tid] = fmax(red2[tid], red2[tid+s]); }
        __syncthreads();
    }
    double rms = 1.0 / sqrt(red[0]/(double)K + 1e-8);
    double s   = 127.0 / fmax(red2[0]*rms, 1e-5);
    signed char* orow = q8 + (size_t)row*K;
    for (int i = tid; i < K; i += 256)
        orow[i] = (signed char)(int)fmin(fmax(rint(rb[i]*rms*s), -128.0), 127.0);
    if (tid == 0) dscale[row] = s;
}

// ---------------- layernorm(+gb/+mod) + rmsnorm + int8 quant (f64) ---------
__global__ void k_lnq8(const double* __restrict__ x, signed char* __restrict__ q8,
                       double* __restrict__ dscale, int K,
                       const float* __restrict__ gamma, const float* __restrict__ beta,
                       const double* __restrict__ sh, const double* __restrict__ sc,
                       int modstride, double eps)
{
    extern __shared__ double rb[];
    __shared__ double red[256], red2[256];
    const int row = blockIdx.x, tid = threadIdx.x;
    const double* xr = x + (size_t)row*K;
    double s1 = 0.0;
    for (int i = tid; i < K; i += 256) { double v = xr[i]; rb[i] = v; s1 += v; }
    red[tid] = s1; __syncthreads();
    for (int s = 128; s > 0; s >>= 1) { if (tid < s) red[tid] += red[tid+s]; __syncthreads(); }
    double mu = red[0]/(double)K;
    __syncthreads();
    double s2 = 0.0;
    for (int i = tid; i < K; i += 256) { double d = rb[i]-mu; s2 += d*d; }
    red[tid] = s2; __syncthreads();
    for (int s = 128; s > 0; s >>= 1) { if (tid < s) red[tid] += red[tid+s]; __syncthreads(); }
    double r = 1.0 / sqrt(red[0]/(double)K + eps);
    const int bn = row >> 8;
    __syncthreads();
    double ss = 0.0, am = 0.0;
    for (int i = tid; i < K; i += 256) {
        double y = (rb[i]-mu)*r;
        if (gamma) y = y*(double)gamma[i] + (double)beta[i];
        if (sh)    y = y*(1.0 + sc[(size_t)bn*modstride + i]) + sh[(size_t)bn*modstride + i];
        rb[i] = y; ss += y*y; am = fmax(am, fabs(y));
    }
    red[tid] = ss; red2[tid] = am;
    __syncthreads();
    for (int s = 128; s > 0; s >>= 1) {
        if (tid < s) { red[tid] += red[tid+s]; red2[tid] = fmax(red2[tid], red2[tid+s]); }
        __syncthreads();
    }
    double rms = 1.0 / sqrt(red[0]/(double)K + 1e-8);
    double s   = 127.0 / fmax(red2[0]*rms, 1e-5);
    signed char* orow = q8 + (size_t)row*K;
    for (int i = tid; i < K; i += 256)
        orow[i] = (signed char)(int)fmin(fmax(rint(rb[i]*rms*s), -128.0), 127.0);
    if (tid == 0) dscale[row] = s;
}

// ---------------- ogate (rmsnorm*g*sig(g)) + rmsnorm + quant (f64) ---------
__global__ void k_ogateq8(const double* __restrict__ O, const double* __restrict__ G,
                          signed char* __restrict__ q8, double* __restrict__ dscale, int K)
{
    extern __shared__ double rb[];
    __shared__ double red[256], red2[256];
    const int row = blockIdx.x, tid = threadIdx.x;
    const double* orow = O + (size_t)row*K;
    const double* grow = G + (size_t)row*K;
    double ss = 0.0;
    for (int i = tid; i < K; i += 256) { double v = orow[i]; rb[i] = v; ss += v*v; }
    red[tid] = ss; __syncthreads();
    for (int s = 128; s > 0; s >>= 1) { if (tid < s) red[tid] += red[tid+s]; __syncthreads(); }
    double rmso = 1.0 / sqrt(red[0]/(double)K + 1e-8);
    __syncthreads();
    double ss2 = 0.0, am = 0.0;
    for (int i = tid; i < K; i += 256) {
        double g = grow[i];
        double y = rb[i]*rmso * g / (1.0 + exp(-g));
        rb[i] = y; ss2 += y*y; am = fmax(am, fabs(y));
    }
    red[tid] = ss2; red2[tid] = am;
    __syncthreads();
    for (int s = 128; s > 0; s >>= 1) {
        if (tid < s) { red[tid] += red[tid+s]; red2[tid] = fmax(red2[tid], red2[tid+s]); }
        __syncthreads();
    }
    double rms = 1.0 / sqrt(red[0]/(double)K + 1e-8);
    double s   = 127.0 / fmax(red2[0]*rms, 1e-5);
    signed char* qrow = q8 + (size_t)row*K;
    for (int i = tid; i < K; i += 256)
        qrow[i] = (signed char)(int)fmin(fmax(rint(rb[i]*rms*s), -128.0), 127.0);
    if (tid == 0) dscale[row] = s;
}

// combined ogate: rows 0..2047 self, 2048..4095 mv, 4096..4607 ref (K=1152)
__global__ void k_ogateq8c3(const double* __restrict__ Os, const double* __restrict__ Gs,
                            const double* __restrict__ Om, const double* __restrict__ Gm,
                            const double* __restrict__ Or, const double* __restrict__ Gr,
                            signed char* __restrict__ q8, double* __restrict__ dscale)
{
    extern __shared__ double rb[];
    __shared__ double red[256], red2[256];
    const int row = blockIdx.x, tid = threadIdx.x;
    const int K = 1152;
    const double *orow, *grow;
    if (row < 2048)      { orow = Os + (size_t)row*K;        grow = Gs + (size_t)row*K; }
    else if (row < 4096) { orow = Om + (size_t)(row-2048)*K; grow = Gm + (size_t)(row-2048)*K; }
    else                 { orow = Or + (size_t)(row-4096)*K; grow = Gr + (size_t)(row-4096)*K; }
    double ss = 0.0;
    for (int i = tid; i < K; i += 256) { double v = orow[i]; rb[i] = v; ss += v*v; }
    red[tid] = ss; __syncthreads();
    for (int s = 128; s > 0; s >>= 1) { if (tid < s) red[tid] += red[tid+s]; __syncthreads(); }
    double rmso = 1.0 / sqrt(red[0]/(double)K + 1e-8);
    __syncthreads();
    double ss2 = 0.0, am = 0.0;
    for (int i = tid; i < K; i += 256) {
        double g = grow[i];
        double y = rb[i]*rmso * g / (1.0 + exp(-g));
        rb[i] = y; ss2 += y*y; am = fmax(am, fabs(y));
    }
    red[tid] = ss2; red2[tid] = am;
    __syncthreads();
    for (int s = 128; s > 0; s >>= 1) {
        if (tid < s) { red[tid] += red[tid+s]; red2[tid] = fmax(red2[tid], red2[tid+s]); }
        __syncthreads();
    }
    double rms = 1.0 / sqrt(red[0]/(double)K + 1e-8);
    double s   = 127.0 / fmax(red2[0]*rms, 1e-5);
    signed char* qrow = q8 + (size_t)row*K;
    for (int i = tid; i < K; i += 256)
        qrow[i] = (signed char)(int)fmin(fmax(rint(rb[i]*rms*s), -128.0), 127.0);
    if (tid == 0) dscale[row] = s;
}

// ---------------- HGRN scans -----------------------------------------------
__global__ void k_gatepre(double* __restrict__ F, double* __restrict__ I, long long n)
{
    long long i = (long long)blockIdx.x*256 + threadIdx.x;
    if (i >= n) return;
    double fp = F[i], ip = I[i];
    double f = 1.0/(1.0+exp(-fp));
    double v = (ip/(1.0+exp(-ip)))*(1.0-f);
    F[i] = f; I[i] = v;
}

__global__ void k_scan2(const double* __restrict__ F, const double* __restrict__ V,
                        double* __restrict__ O, int n_outer, long long outer_stride,
                        int n_inner, long long t_stride, int T)
{
    long long chain = (long long)blockIdx.x*blockDim.x + threadIdx.x;
    if (chain >= (long long)n_outer*n_inner) return;
    long long base = (chain / n_inner)*outer_stride + (chain % n_inner);
    double h = 0.0;
    for (int t = 0; t < T; ++t) {
        long long idx = base + (long long)t*t_stride;
        h = F[idx]*h + V[idx];
        O[idx] = h;
    }
}

__global__ void k_scan3(const double* __restrict__ F, const double* __restrict__ Isilu,
                        double* __restrict__ O, int n_outer, long long outer_stride,
                        int n_inner, long long t_stride, int T)
{
    long long chain = (long long)blockIdx.x*blockDim.x + threadIdx.x;
    if (chain >= (long long)n_outer*n_inner) return;
    long long base = (chain / n_inner)*outer_stride + (chain % n_inner);
    double h = 0.0;
    for (int t = 0; t < T; ++t) {
        long long idx = base + (long long)t*t_stride;
        double f = F[idx];
        double v = Isilu[idx]*(1.0-f);
        h = f*h + v;
        O[idx] = h;
    }
}

// combined self+mv+ref scan:
// chains [0,9216) self T=256; [9216, 9216+589824) mv T=4; rest ref T=256
__global__ void k_scanc3(const double* __restrict__ Fs, const double* __restrict__ Is,
                         const double* __restrict__ Fm, const double* __restrict__ Im,
                         const double* __restrict__ Fr, const double* __restrict__ Ir,
                         double* __restrict__ Osf, double* __restrict__ Omv,
                         double* __restrict__ Orf)
{
    long long cid = (long long)blockIdx.x*blockDim.x + threadIdx.x;
    if (cid < 9216) {
        long long base = (cid / 1152)*294912LL + (cid % 1152);
        double h = 0.0;
        for (int t = 0; t < 256; ++t) {
            long long idx = base + (long long)t*1152;
            double f = Fs[idx];
            double v = Is[idx]*(1.0-f);
            h = f*h + v;
            Osf[idx] = h;
        }
    } else if (cid < 9216 + 589824LL) {
        long long c2 = cid - 9216;
        long long base = (c2 / 294912)*1179648LL + (c2 % 294912);
        double h = 0.0;
        for (int t = 0; t < 4; ++t) {
            long long idx = base + (long long)t*294912;
            double f = Fm[idx];
            double v = Im[idx]*(1.0-f);
            h = f*h + v;
            Omv[idx] = h;
        }
    } else {
        long long c3 = cid - 9216 - 589824LL;
        if (c3 >= 2304) return;
        long long base = (c3 / 1152)*294912LL + (c3 % 1152);
        double h = 0.0;
        for (int t = 0; t < 256; ++t) {
            long long idx = base + (long long)t*1152;
            double f = Fr[idx];
            double v = Ir[idx]*(1.0-f);
            h = f*h + v;
            Orf[idx] = h;
        }
    }
}

// ---------------- misc elementwise (f64) -----------------------------------
__global__ void k_add(const double* __restrict__ a, const double* __restrict__ b,
                      double* __restrict__ o, int n)
{
    int i = blockIdx.x*256 + threadIdx.x;
    if (i < n) o[i] = a[i] + b[i];
}

__global__ void k_resid_attn(double* __restrict__ xt, const double* __restrict__ acc,
                             const double* __restrict__ refo, const double* __restrict__ mod)
{
    int idx = blockIdx.x*256 + threadIdx.x;            // 2048*1152 exact
    int r = idx / 1152, d = idx - r*1152;
    int bn = r >> 8, l = r & 255;
    double ga = mod[(size_t)bn*6912 + 2*1152 + d];
    double rv = refo[((size_t)((bn>>2)*256 + l))*1152 + d];
    xt[idx] += ga*(acc[idx] + rv);
}

// fused-path residual: ga*((self+mv)+ref) — same add order as old accum path
__global__ void k_resid_attn2(double* __restrict__ xt, const double* __restrict__ acc,
                              const double* __restrict__ mvb, const double* __restrict__ refo,
                              const double* __restrict__ mod)
{
    int idx = blockIdx.x*256 + threadIdx.x;            // 2048*1152 exact
    int r = idx / 1152, d = idx - r*1152;
    int bn = r >> 8, l = r & 255;
    double ga = mod[(size_t)bn*6912 + 2*1152 + d];
    double rv = refo[((size_t)((bn>>2)*256 + l))*1152 + d];
    xt[idx] += ga*((acc[idx] + mvb[idx]) + rv);
}

__global__ void k_resid_mlp(double* __restrict__ xt, const double* __restrict__ t2,
                            const double* __restrict__ mod)
{
    int idx = blockIdx.x*256 + threadIdx.x;
    int r = idx / 1152, d = idx - r*1152;
    int bn = r >> 8;
    xt[idx] += mod[(size_t)bn*6912 + 5*1152 + d] * t2[idx];
}

__global__ void k_patchify(const float* __restrict__ x, const float* __restrict__ w,
                           const float* __restrict__ bias, const float* __restrict__ pos,
                           const double* __restrict__ f0, double* __restrict__ xt)
{
    int idx = blockIdx.x*256 + threadIdx.x;            // 2048*1152 exact
    int r = idx / 1152, o = idx - r*1152;
    int bn = r >> 8, p = r & 255;
    int y = p >> 4, xx = p & 15;
    double acc = (double)bias[o] + (double)pos[(size_t)p*1152 + o] + f0[idx];
#pragma unroll
    for (int c = 0; c < 4; ++c)
#pragma unroll
        for (int ky = 0; ky < 2; ++ky)
#pragma unroll
            for (int kx = 0; kx < 2; ++kx)
                acc += (double)x[((size_t)(bn*4 + c)*32 + 2*y+ky)*32 + 2*xx+kx]
                     * (double)w[o*16 + c*4 + ky*2 + kx];
    xt[idx] = acc;
}

__global__ void k_unpatch(const double* __restrict__ flo, float* __restrict__ out)
{
    int idx = blockIdx.x*256 + threadIdx.x;            // 65536 exact
    int xx = idx & 31, y = (idx>>5)&31, ch = (idx>>10)&7, b = idx>>13;
    int hp = y>>1, py = y&1, wp = xx>>1, px = xx&1;
    out[idx] = (float)flo[((size_t)(b*256 + hp*16 + wp))*32 + (py*2+px)*8 + ch];
}

// ---------------- f64 GEMM: probed MFMA (64x64, BK=32) — proven r13/r16 ----
template<int AMODE>
DEV void load_a4d(const void* __restrict__ A, int row, int k, int M, double o[4])
{
    if (row >= M) { o[0]=o[1]=o[2]=o[3]=0.0; return; }
    if constexpr (AMODE == 1) {
        const float* Af = (const float*)A;
        int b = row>>10, p = row&1023, oy = p>>5, ox = p&31;
        int c = k>>8, ky = (k>>4)&15, kx = k&15;
        float4 v = *reinterpret_cast<const float4*>(
            Af + (((size_t)(b*6+c)*512 + (size_t)(oy*16+ky))*512 + (size_t)(ox*16+kx)));
        o[0]=v.x; o[1]=v.y; o[2]=v.z; o[3]=v.w;
    } else {
        const double* Ad = (const double*)A;
        int b = row>>8, y = (row>>4)&15, x = row&15;
        int q = k/1152, c = k - q*1152, ky = q>>1, kx = q&1;
        const double* p = Ad + (size_t)(b*1024 + (2*y+ky)*32 + 2*x+kx)*1152 + c;
        o[0]=p[0]; o[1]=p[1]; o[2]=p[2]; o[3]=p[3];
    }
}

template<int WMODE>
DEV void load_w4d(const float* __restrict__ W, int row, int k, int Nb, int K, double o[4])
{
    if (row >= Nb) { o[0]=o[1]=o[2]=o[3]=0.0; return; }
    if constexpr (WMODE == 0) {
        float4 v = *reinterpret_cast<const float4*>(W + (size_t)row*K + k);
        o[0]=v.x; o[1]=v.y; o[2]=v.z; o[3]=v.w;
    } else {
        int q = k/1152, c = k - q*1152;
        const float* p = W + (size_t)row*4608 + (size_t)c*4 + q;
        o[0]=p[0]; o[1]=p[4]; o[2]=p[8]; o[3]=p[12];
    }
}

template<int AMODE, int WMODE>
__global__ __launch_bounds__(256)
void k_dgemm(const void* __restrict__ A, const float* __restrict__ W,
             const float* __restrict__ bias, double* __restrict__ C,
             int M, int N, int K, int gridx, const int* __restrict__ mfma_flag)
{
    __shared__ double As[64][33];                  // [m][k0..31], +1 pad
    __shared__ double Ws[64][33];                  // [n][k0..31]
    const int tid = threadIdx.x;
    const int2 bxy = xcd_swz(gridx);
    const int m0 = bxy.y*64, n0 = bxy.x*64;
    const int lr = tid >> 2;                       // staging row 0..63
    const int lc = (tid & 3) * 4;                  // staging k {0,4,8,12}
    const int flag = *mfma_flag;                   // uniform

    if (flag) {
        const int cmb = flag - 1;
        const int a_alt = cmb & 1, b_alt = (cmb >> 1) & 1, dv = (cmb >> 2) & 3;
        const int lane = tid & 63, wid = tid >> 6;
        const int wm = wid >> 1, wn = wid & 1;     // 2x2 waves of 32x32
        const int ai = a_alt ? (lane >> 2) : (lane & 15);
        const int ak = a_alt ? (lane & 3)  : (lane >> 4);
        const int bj = b_alt ? (lane >> 2) : (lane & 15);
        const int bk = b_alt ? (lane & 3)  : (lane >> 4);
        f64x4 fa[2][2];
#pragma unroll
        for (int i = 0; i < 2; ++i)
#pragma unroll
            for (int j = 0; j < 2; ++j) fa[i][j] = f64x4{0.0,0.0,0.0,0.0};

        for (int kt = 0; kt < K; kt += 32) {       // BK=32
#pragma unroll
            for (int h = 0; h < 2; ++h) {
                double v[4];
                load_a4d<AMODE>(A, m0+lr, kt + h*16 + lc, M, v);
                As[lr][h*16+lc+0]=v[0]; As[lr][h*16+lc+1]=v[1];
                As[lr][h*16+lc+2]=v[2]; As[lr][h*16+lc+3]=v[3];
                double wv[4];
                load_w4d<WMODE>(W, n0+lr, kt + h*16 + lc, N, K, wv);
                Ws[lr][h*16+lc+0]=wv[0]; Ws[lr][h*16+lc+1]=wv[1];
                Ws[lr][h*16+lc+2]=wv[2]; Ws[lr][h*16+lc+3]=wv[3];
            }
            __syncthreads();
#pragma unroll
            for (int k4 = 0; k4 < 8; ++k4) {       // sequential k order preserved
                double a0 = As[wm*32 + ai][k4*4 + ak];
                double a1 = As[wm*32 + 16 + ai][k4*4 + ak];
                double b0 = Ws[wn*32 + bj][k4*4 + bk];
                double b1 = Ws[wn*32 + 16 + bj][k4*4 + bk];
                fa[0][0] = __builtin_amdgcn_mfma_f64_16x16x4f64(a0, b0, fa[0][0], 0, 0, 0);
                fa[0][1] = __builtin_amdgcn_mfma_f64_16x16x4f64(a0, b1, fa[0][1], 0, 0, 0);
                fa[1][0] = __builtin_amdgcn_mfma_f64_16x16x4f64(a1, b0, fa[1][0], 0, 0, 0);
                fa[1][1] = __builtin_amdgcn_mfma_f64_16x16x4f64(a1, b1, fa[1][1], 0, 0, 0);
            }
            __syncthreads();
        }
#pragma unroll
        for (int i = 0; i < 2; ++i)
#pragma unroll
            for (int j = 0; j < 2; ++j)
#pragma unroll
                for (int r = 0; r < 4; ++r) {
                    int ir = (dv & 2) ? (4*r + (lane >> 4)) : (4*(lane >> 4) + r);
                    int ic = lane & 15;
                    if (dv & 1) { int t = ir; ir = ic; ic = t; }
                    int row = m0 + wm*32 + i*16 + ir;
                    int col = n0 + wn*32 + j*16 + ic;
                    if (row < M && col < N)
                        C[(size_t)row*N + col] = fa[i][j][r] + (bias ? (double)bias[col] : 0.0);
                }
        return;
    }

    // ---- SIMT fallback (proven rounds 3-16; BK=16) ----
    const int tx = tid & 15, ty = tid >> 4;
    double acc[4][4] = {};
    for (int kt = 0; kt < K; kt += 16) {
        {
            double v[4];
            load_a4d<AMODE>(A, m0+lr, kt+lc, M, v);
            As[lr][lc+0]=v[0]; As[lr][lc+1]=v[1]; As[lr][lc+2]=v[2]; As[lr][lc+3]=v[3];
        }
        {
            double wv[4];
            load_w4d<WMODE>(W, n0+lr, kt+lc, N, K, wv);
            Ws[lr][lc+0]=wv[0]; Ws[lr][lc+1]=wv[1]; Ws[lr][lc+2]=wv[2]; Ws[lr][lc+3]=wv[3];
        }
        __syncthreads();
#pragma unroll
        for (int k = 0; k < 16; ++k) {
            double a[4], b[4];
#pragma unroll
            for (int e = 0; e < 4; ++e) { a[e] = As[ty + 16*e][k]; b[e] = Ws[tx + 16*e][k]; }
#pragma unroll
            for (int i = 0; i < 4; ++i)
#pragma unroll
                for (int j = 0; j < 4; ++j) acc[i][j] += a[i]*b[j];
        }
        __syncthreads();
    }
#pragma unroll
    for (int i = 0; i < 4; ++i) {
        int row = m0 + ty + 16*i;
        if (row >= M) continue;
#pragma unroll
        for (int j = 0; j < 4; ++j) {
            int col = n0 + tx + 16*j;
            if (col >= N) continue;
            C[(size_t)row*N + col] = acc[i][j] + (bias ? (double)bias[col] : 0.0);
        }
    }
}

// ---------------- int8 MFMA GEMM (exact), BK=128, XCD swizzle --------------
template<int GATE, int PRE>
__global__ __launch_bounds__(256)
void k_qgemm(const signed char* __restrict__ A8, const double* __restrict__ ascale,
             const float* __restrict__ Wf, const signed char* __restrict__ W8,
             const double* __restrict__ wsum, long long wcount,
             const float* __restrict__ bias, double* __restrict__ C,
             int M, int N, int K, int accum, int gridM)
{
    __shared__ __align__(16) signed char Als[8][128][16];
    __shared__ __align__(16) signed char Bls[8][128][16];
    __shared__ __align__(16) signed char B2ls[GATE?8:1][GATE?128:1][16];
    const int tid = threadIdx.x;
    const int lane = tid & 63, wid = tid >> 6;
    const int wr = wid >> 1, wc = wid & 1;             // 2x2 waves, 64x64 each
    const int2 bxy = xcd_swz(gridM);
    const int m0 = bxy.x*128, n0 = bxy.y*128;
    const int ks = lane >> 4, fr = lane & 15;

    const double dqw = fmax(*wsum / (double)wcount, 1e-5);
    const double thr = 0.5 * dqw;

    i32x4 acc[4][4];
    i32x4 acc2[GATE?4:1][4];
#pragma unroll
    for (int i = 0; i < 4; ++i)
#pragma unroll
        for (int j = 0; j < 4; ++j) {
            acc[i][j] = i32x4{0,0,0,0};
            if constexpr (GATE) acc2[i][j] = i32x4{0,0,0,0};
        }

    for (int kt = 0; kt < K; kt += 128) {
#pragma unroll
        for (int c = 0; c < 4; ++c) {
            int idx = tid + c*256;
            int row = idx & 127, kslot = idx >> 7;
            i32x4 v = {0,0,0,0};
            if (m0 + row < M)
                v = *reinterpret_cast<const i32x4*>(A8 + (size_t)(m0+row)*K + kt + kslot*16);
            *reinterpret_cast<i32x4*>(&Als[kslot][row][0]) = v;
        }
#pragma unroll
        for (int c = 0; c < 4; ++c) {
            int idx = tid + c*256;
            int row = idx & 127, kslot = idx >> 7;
            i32x4 pv = {0,0,0,0};
            if (n0 + row < N) {
                if constexpr (PRE) {
                    pv = *reinterpret_cast<const i32x4*>(W8 + (size_t)(n0+row)*K + kt + kslot*16);
                } else {
                    const float* wp = Wf + (size_t)(n0+row)*K + kt + kslot*16;
#pragma unroll
                    for (int d = 0; d < 4; ++d) {
                        float4 wv = *reinterpret_cast<const float4*>(wp + d*4);
                        float we[4] = {wv.x, wv.y, wv.z, wv.w};
                        unsigned p = 0;
#pragma unroll
                        for (int e = 0; e < 4; ++e) {
                            double wd = (double)we[e];
                            int q = (wd > thr) - (wd < -thr);
                            p |= ((unsigned)(q & 255)) << (8*e);
                        }
                        pv[d] = (int)p;
                    }
                }
            }
            *reinterpret_cast<i32x4*>(&Bls[kslot][row][0]) = pv;
        }
        if constexpr (GATE) {
#pragma unroll
            for (int c = 0; c < 4; ++c) {
                int idx = tid + c*256;
                int row = idx & 127, kslot = idx >> 7;
                i32x4 pv = {0,0,0,0};
                if (n0 + row < N) {
                    if constexpr (PRE) {
                        pv = *reinterpret_cast<const i32x4*>(W8 + (size_t)(n0+row+N)*K + kt + kslot*16);
                    } else {
                        const float* wp = Wf + (size_t)(n0+row+N)*K + kt + kslot*16;
#pragma unroll
                        for (int d = 0; d < 4; ++d) {
                            float4 wv = *reinterpret_cast<const float4*>(wp + d*4);
                            float we[4] = {wv.x, wv.y, wv.z, wv.w};
                            unsigned p = 0;
#pragma unroll
                            for (int e = 0; e < 4; ++e) {
                                double wd = (double)we[e];
                                int q = (wd > thr) - (wd < -thr);
                                p |= ((unsigned)(q & 255)) << (8*e);
                            }
                            pv[d] = (int)p;
                        }
                    }
                }
                *reinterpret_cast<i32x4*>(&B2ls[kslot][row][0]) = pv;
            }
        }
        __syncthreads();
#pragma unroll
        for (int kk = 0; kk < 2; ++kk) {
            const int kb = kk*4 + ks;
            i32x4 a[4];
#pragma unroll
            for (int i = 0; i < 4; ++i)
                a[i] = *reinterpret_cast<const i32x4*>(&Als[kb][wr*64 + i*16 + fr][0]);
#pragma unroll
            for (int j = 0; j < 4; ++j) {
                i32x4 b = *reinterpret_cast<const i32x4*>(&Bls[kb][wc*64 + j*16 + fr][0]);
#pragma unroll
                for (int i = 0; i < 4; ++i)
                    acc[i][j] = __builtin_amdgcn_mfma_i32_16x16x64_i8(a[i], b, acc[i][j], 0, 0, 0);
                if constexpr (GATE) {
                    i32x4 b2 = *reinterpret_cast<const i32x4*>(&B2ls[kb][wc*64 + j*16 + fr][0]);
#pragma unroll
                    for (int i = 0; i < 4; ++i)
                        acc2[i][j] = __builtin_amdgcn_mfma_i32_16x16x64_i8(a[i], b2, acc2[i][j], 0, 0, 0);
                }
            }
        }
        __syncthreads();
    }

#pragma unroll
    for (int i = 0; i < 4; ++i) {
#pragma unroll
        for (int r = 0; r < 4; ++r) {
            int row = m0 + wr*64 + i*16 + (lane>>4)*4 + r;
            if (row >= M) continue;
            double mul = dqw / ascale[row];
#pragma unroll
            for (int j = 0; j < 4; ++j) {
                int col = n0 + wc*64 + j*16 + (lane & 15);
                if (col >= N) continue;
                size_t o = (size_t)row*N + col;
                if constexpr (GATE) {
                    double g = (double)acc[i][j][r] * mul;
                    double y = (double)acc2[i][j][r] * mul;
                    C[o] = g/(1.0+exp(-g)) * y;
                } else {
                    double v = (double)acc[i][j][r] * mul;
                    if (bias) v += (double)bias[col];
                    C[o] = accum ? C[o] + v : v;
                }
            }
        }
    }
}

// ---------------- fused f/i/g GEMM (3 groups, fallback helper) -------------
__global__ __launch_bounds__(256)
void k_qgemm3(const signed char* __restrict__ A8, const double* __restrict__ ascale,
              W3 w3, long long wcount, int M, int gridM)
{
    __shared__ __align__(16) signed char Als[8][128][16];
    __shared__ __align__(16) signed char Bls[8][128][16];
    const int tid = threadIdx.x;
    const int lane = tid & 63, wid = tid >> 6;
    const int wr = wid >> 1, wc = wid & 1;
    const int2 bxy = xcd_swz(gridM);
    const int m0 = bxy.x*128;
    const int yy = bxy.y;
    const int g = yy / 9, nt = yy - g*9;
    const int n0 = nt*128;
    const signed char* W8 = w3.w[g];
    double* C = w3.c[g];
    const int ks = lane >> 4, fr = lane & 15;

    const double dqw = fmax(*w3.sc[g] / (double)wcount, 1e-5);

    i32x4 acc[4][4];
#pragma unroll
    for (int i = 0; i < 4; ++i)
#pragma unroll
        for (int j = 0; j < 4; ++j) acc[i][j] = i32x4{0,0,0,0};

    for (int kt = 0; kt < 1152; kt += 128) {
#pragma unroll
        for (int c = 0; c < 4; ++c) {
            int idx = tid + c*256;
            int row = idx & 127, kslot = idx >> 7;
            i32x4 v = {0,0,0,0};
            if (m0 + row < M)
                v = *reinterpret_cast<const i32x4*>(A8 + (size_t)(m0+row)*1152 + kt + kslot*16);
            *reinterpret_cast<i32x4*>(&Als[kslot][row][0]) = v;
        }
#pragma unroll
        for (int c = 0; c < 4; ++c) {
            int idx = tid + c*256;
            int row = idx & 127, kslot = idx >> 7;
            i32x4 pv = *reinterpret_cast<const i32x4*>(W8 + (size_t)(n0+row)*1152 + kt + kslot*16);
            *reinterpret_cast<i32x4*>(&Bls[kslot][row][0]) = pv;
        }
        __syncthreads();
#pragma unroll
        for (int kk = 0; kk < 2; ++kk) {
            const int kb = kk*4 + ks;
            i32x4 a[4];
#pragma unroll
            for (int i = 0; i < 4; ++i)
                a[i] = *reinterpret_cast<const i32x4*>(&Als[kb][wr*64 + i*16 + fr][0]);
#pragma unroll
            for (int j = 0; j < 4; ++j) {
                i32x4 b = *reinterpret_cast<const i32x4*>(&Bls[kb][wc*64 + j*16 + fr][0]);
#pragma unroll
                for (int i = 0; i < 4; ++i)
                    acc[i][j] = __builtin_amdgcn_mfma_i32_16x16x64_i8(a[i], b, acc[i][j], 0, 0, 0);
            }
        }
        __syncthreads();
    }

    const int gm3 = g % 3;
#pragma unroll
    for (int i = 0; i < 4; ++i) {
#pragma unroll
        for (int r = 0; r < 4; ++r) {
            int row = m0 + wr*64 + i*16 + (lane>>4)*4 + r;
            if (row >= M) continue;
            double mul = dqw / ascale[row];
#pragma unroll
            for (int j = 0; j < 4; ++j) {
                int col = n0 + wc*64 + j*16 + (lane & 15);
                double v = (double)acc[i][j][r] * mul;
                if (gm3 == 0)      v = 1.0/(1.0+exp(-v));
                else if (gm3 == 1) v = v/(1.0+exp(-v));
                C[(size_t)row*1152 + col] = v;
            }
        }
    }
}

// ---------------- fused self+mv+ref projections (9 groups) -----------------
__global__ __launch_bounds__(256)
void k_qgemm9(const signed char* __restrict__ A8s, const double* __restrict__ ascs,
              const signed char* __restrict__ A8r, const double* __restrict__ ascr,
              W9 w9, long long wcount)
{
    __shared__ __align__(16) signed char Als[8][128][16];
    __shared__ __align__(16) signed char Bls[8][128][16];
    const int tid = threadIdx.x;
    const int lane = tid & 63, wid = tid >> 6;
    const int wr = wid >> 1, wc = wid & 1;
    const int lb = xcd_swz(1).y;
    int m0, g, nt;
    const signed char* A8;
    const double* ascale;
    if (lb < 864) {
        m0 = (lb % 16)*128;
        int yy = lb / 16;
        g = yy / 9; nt = yy - g*9;
        A8 = A8s; ascale = ascs;
    } else {
        int l2 = lb - 864;
        m0 = (l2 % 4)*128;
        int yy2 = l2 / 4;
        g = 6 + yy2 / 9; nt = yy2 % 9;
        A8 = A8r; ascale = ascr;
    }
    const int n0 = nt*128;
    const signed char* W8 = w9.w[g];
    double* C = w9.c[g];
    const int ks = lane >> 4, fr = lane & 15;

    const double dqw = fmax(*w9.sc[g] / (double)wcount, 1e-5);

    i32x4 acc[4][4];
#pragma unroll
    for (int i = 0; i < 4; ++i)
#pragma unroll
        for (int j = 0; j < 4; ++j) acc[i][j] = i32x4{0,0,0,0};

    for (int kt = 0; kt < 1152; kt += 128) {
#pragma unroll
        for (int c = 0; c < 4; ++c) {
            int idx = tid + c*256;
            int row = idx & 127, kslot = idx >> 7;
            i32x4 v = *reinterpret_cast<const i32x4*>(A8 + (size_t)(m0+row)*1152 + kt + kslot*16);
            *reinterpret_cast<i32x4*>(&Als[kslot][row][0]) = v;
        }
#pragma unroll
        for (int c = 0; c < 4; ++c) {
            int idx = tid + c*256;
            int row = idx & 127, kslot = idx >> 7;
            i32x4 pv = *reinterpret_cast<const i32x4*>(W8 + (size_t)(n0+row)*1152 + kt + kslot*16);
            *reinterpret_cast<i32x4*>(&Bls[kslot][row][0]) = pv;
        }
        __syncthreads();
#pragma unroll
        for (int kk = 0; kk < 2; ++kk) {
            const int kb = kk*4 + ks;
            i32x4 a[4];
#pragma unroll
            for (int i = 0; i < 4; ++i)
                a[i] = *reinterpret_cast<const i32x4*>(&Als[kb][wr*64 + i*16 + fr][0]);
#pragma unroll
            for (int j = 0; j < 4; ++j) {
                i32x4 b = *reinterpret_cast<const i32x4*>(&Bls[kb][wc*64 + j*16 + fr][0]);
#pragma unroll
                for (int i = 0; i < 4; ++i)
                    acc[i][j] = __builtin_amdgcn_mfma_i32_16x16x64_i8(a[i], b, acc[i][j], 0, 0, 0);
            }
        }
        __syncthreads();
    }

    const int gm3 = g % 3;    // 0=f->sigma, 1=i->silu, 2=g->raw
#pragma unroll
    for (int i = 0; i < 4; ++i) {
#pragma unroll
        for (int r = 0; r < 4; ++r) {
            int row = m0 + wr*64 + i*16 + (lane>>4)*4 + r;
            double mul = dqw / ascale[row];
#pragma unroll
            for (int j = 0; j < 4; ++j) {
                int col = n0 + wc*64 + j*16 + (lane & 15);
                double v = (double)acc[i][j][r] * mul;
                if (gm3 == 0)      v = 1.0/(1.0+exp(-v));
                else if (gm3 == 1) v = v/(1.0+exp(-v));
                C[(size_t)row*1152 + col] = v;
            }
        }
    }
}

// combined self+mv+ref o-projection.
__global__ __launch_bounds__(256)
void k_qgemmO3(const signed char* __restrict__ A8, const double* __restrict__ ascale,
               const signed char* __restrict__ Ws8, const signed char* __restrict__ Wm8,
               const signed char* __restrict__ Wr8,
               const double* __restrict__ scs, const double* __restrict__ scm,
               const double* __restrict__ scr, long long wcount,
               double* __restrict__ Cs, double* __restrict__ Cm, double* __restrict__ Cr)
{
    __shared__ __align__(16) signed char Als[8][128][16];
    __shared__ __align__(16) signed char Bls[8][128][16];
    const int tid = threadIdx.x;
    const int lane = tid & 63, wid = tid >> 6;
    const int wr = wid >> 1, wc = wid & 1;
    const int lb = xcd_swz(1).y;
    int m0, nt;
    const signed char* W8;
    const signed char* A;
    const double* as;
    double* C;
    double scv;
    if (lb < 144)      { m0 = (lb % 16)*128; nt = lb / 16; W8 = Ws8; A = A8;
                         as = ascale; C = Cs; scv = *scs; }
    else if (lb < 288) { int l2 = lb - 144; m0 = (l2 % 16)*128; nt = l2 / 16; W8 = Wm8;
                         A = A8 + (size_t)2048*1152; as = ascale + 2048; C = Cm; scv = *scm; }
    else               { int l3 = lb - 288; m0 = (l3 % 4)*128; nt = l3 / 4; W8 = Wr8;
                         A = A8 + (size_t)4096*1152; as = ascale + 4096; C = Cr; scv = *scr; }
    const int n0 = nt*128;
    const int ks = lane >> 4, fr = lane & 15;

    const double dqw = fmax(scv / (double)wcount, 1e-5);

    i32x4 acc[4][4];
#pragma unroll
    for (int i = 0; i < 4; ++i)
#pragma unroll
        for (int j = 0; j < 4; ++j) acc[i][j] = i32x4{0,0,0,0};

    for (int kt = 0; kt < 1152; kt += 128) {
#pragma unroll
        for (int c = 0; c < 4; ++c) {
            int idx = tid + c*256;
            int row = idx & 127, kslot = idx >> 7;
            i32x4 v = *reinterpret_cast<const i32x4*>(A + (size_t)(m0+row)*1152 + kt + kslot*16);
            *reinterpret_cast<i32x4*>(&Als[kslot][row][0]) = v;
        }
#pragma unroll
        for (int c = 0; c < 4; ++c) {
            int idx = tid + c*256;
            int row = idx & 127, kslot = idx >> 7;
            i32x4 pv = *reinterpret_cast<const i32x4*>(W8 + (size_t)(n0+row)*1152 + kt + kslot*16);
            *reinterpret_cast<i32x4*>(&Bls[kslot][row][0]) = pv;
        }
        __syncthreads();
#pragma unroll
        for (int kk = 0; kk < 2; ++kk) {
            const int kb = kk*4 + ks;
            i32x4 a[4];
#pragma unroll
            for (int i = 0; i < 4; ++i)
                a[i] = *reinterpret_cast<const i32x4*>(&Als[kb][wr*64 + i*16 + fr][0]);
#pragma unroll
            for (int j = 0; j < 4; ++j) {
                i32x4 b = *reinterpret_cast<const i32x4*>(&Bls[kb][wc*64 + j*16 + fr][0]);
#pragma unroll
                for (int i = 0; i < 4; ++i)
                    acc[i][j] = __builtin_amdgcn_mfma_i32_16x16x64_i8(a[i], b, acc[i][j], 0, 0, 0);
            }
        }
        __syncthreads();
    }

#pragma unroll
    for (int i = 0; i < 4; ++i) {
#pragma unroll
        for (int r = 0; r < 4; ++r) {
            int row = m0 + wr*64 + i*16 + (lane>>4)*4 + r;
            double mul = dqw / as[row];
#pragma unroll
            for (int j = 0; j < 4; ++j) {
                int col = n0 + wc*64 + j*16 + (lane & 15);
                C[(size_t)row*1152 + col] = (double)acc[i][j][r] * mul;
            }
        }
    }
}

// ---------------------------------------------------------------------------
extern "C" void kernel_launch(void* const* d_in, const int* in_sizes, int n_in,
                              void* d_out, int out_size, void* d_ws, size_t ws_size,
                              hipStream_t stream)
{
    (void)in_sizes; (void)n_in; (void)out_size;
    auto in = [&](int i){ return (const float*)d_in[i]; };

    const float *X = in(0), *T = in(1), *Y = in(2), *XC = in(3), *REF = in(4);
    const float *xe_w = in(6), *xe_b = in(7), *pos = in(8);
    const float *te_w1 = in(9), *te_b1 = in(10), *te_w2 = in(11), *te_b2 = in(12);
    const float *pp_w = in(13), *pp_b = in(14);
    const float *sa_pe_w = in(15), *sa_pe_b = in(16);
    const float *sa_ln_g = in(17), *sa_ln_b = in(18);
    const float *sa_gate_w = in(19), *sa_down_w = in(20);
    const float *sa_dc_w = in(21), *sa_dc_b = in(22);
    const float *ada_w = in(23), *ada_b = in(24);
    const float *sa_wi = in(25), *sa_wf = in(26), *sa_wg = in(27), *sa_wo = in(28);
    const float *mv_wi = in(29), *mv_wf = in(30), *mv_wg = in(31), *mv_wo = in(32);
    const float *rf_wi = in(33), *rf_wf = in(34), *rf_wg = in(35), *rf_wo = in(36);
    const float *gate_w = in(37), *down_w = in(38);
    const float *fl_w = in(39), *fl_b = in(40), *fl_ada_w = in(41), *fl_ada_b = in(42);
    float* OUT = (float*)d_out;

    // ---------- workspace layout ----------
    size_t off = 0;
    auto AL = [&](size_t bytes){ off = (off+255)&~(size_t)255; size_t r = off; off += bytes; return r; };
    const size_t oScale = AL(37*8);
    const size_t oPart  = AL(37*32*8);
    const size_t oProbe = AL(64*4*8);
    const size_t oFlag  = AL(256);
    const size_t oSM1 = AL(8*1152*8), oSM2 = AL(8*1152*8), oSM3 = AL(8*1152*8);
    const size_t oCB  = AL(8*1152*8);
    const size_t oMOD = AL(8*6912*8);
    const size_t oH   = AL((size_t)8192*1152*8);    // 75.5 MB; OB_self/OB_mv/OB_ref
    const size_t oINT = AL((size_t)1024*4608*8);    // 37.7 MB; FB2/IB2/MVB later
    const size_t oF0  = AL((size_t)2048*1152*8);    // also ACC
    const size_t oXT  = AL((size_t)2048*1152*8);
    const size_t oFB  = AL((size_t)2048*1152*8);
    const size_t oIB  = AL((size_t)2048*1152*8);
    const size_t oGB  = AL((size_t)2048*1152*8);
    const size_t oGB2 = AL((size_t)2048*1152*8);    // mv g (fused path)
    const size_t oFBr = AL((size_t)512*1152*8);     // ref f (fused path)
    const size_t oIBr = AL((size_t)512*1152*8);     // ref i
    const size_t oGBr = AL((size_t)512*1152*8);     // ref g
    const size_t oRO  = AL((size_t)512*1152*8);
    const size_t oQ8X = AL((size_t)2048*1152);
    const size_t oQ8I = AL((size_t)1024*4608);
    const size_t oQ8O = AL((size_t)2048*1152);
    const size_t oQ8O2= AL((size_t)4608*1152);      // fused self+mv+ref ogate out
    const size_t oQ8R = AL((size_t)512*1152);
    const size_t oQ8T = AL((size_t)8*1152);
    const size_t oQ8C = AL((size_t)8*1152);
    const size_t oDSX = AL(2048*8), oDSI = AL(1024*8), oDSO = AL(2048*8);
    const size_t oDSO2= AL(4608*8);
    const size_t oDSR = AL(512*8),  oDST = AL(8*8),    oDSC = AL(8*8);
    if (off > ws_size) return;

    // ---------- weight list + optional pre-ternarized region ----------
    WList wl{}; WOffs wo{};
    long long wn[37];
    int nw = 0;
    auto addw = [&](const float* w, long long n){ wl.p[nw]=w; wl.n[nw]=n; wn[nw]=n; nw++; };
    addw(te_w1, 294912); addw(te_w2, 1327104); addw(pp_w, 884736);
    addw(sa_gate_w, 10616832); addw(sa_down_w, 5308416);
    for (int l = 0; l < 2; ++l) {
        addw(ada_w + (size_t)l*7962624, 7962624);
        addw(sa_wi + (size_t)l*1327104, 1327104);
        addw(sa_wf + (size_t)l*1327104, 1327104);
        addw(sa_wg + (size_t)l*1327104, 1327104);
        addw(sa_wo + (size_t)l*1327104, 1327104);
        addw(mv_wi + (size_t)l*1327104, 1327104);
        addw(mv_wf + (size_t)l*1327104, 1327104);
        addw(mv_wg + (size_t)l*1327104, 1327104);
        addw(mv_wo + (size_t)l*1327104, 1327104);
        addw(rf_wi + (size_t)l*1327104, 1327104);
        addw(rf_wf + (size_t)l*1327104, 1327104);
        addw(rf_wg + (size_t)l*1327104, 1327104);
        addw(rf_wo + (size_t)l*1327104, 1327104);
        addw(gate_w + (size_t)l*10616832, 10616832);
        addw(down_w + (size_t)l*5308416, 5308416);
    }
    addw(fl_ada_w, 2654208); addw(fl_w, 36864);

    size_t off_saved = off;
    long long wtot = 0;
    for (int i = 0; i < 37; ++i) { wo.o[i] = wtot; wtot += (wn[i] + 255) & ~255LL; }
    const size_t oW8 = AL((size_t)wtot);
    const bool useW8 = (off <= ws_size);
    if (!useW8) off = off_saved;

    // ---------- optional transposed down-conv weight (f32, 21 MB) ----------
    size_t off_wt = off;
    const size_t oWt = AL((size_t)1152*4608*4);
    const bool useWt = (off <= ws_size);
    if (!useWt) off = off_wt;

    // ---------- tiered SA/MLP chunk enlargement (row-independent) ----------
    int schunk = 1024;
    size_t oINTb = 0, oQ8Ib = 0, oQ8Xb = 0, oDSXb = 0, oDSIb = 0;
    if (useW8) {
        size_t off_w8 = off;
        oINTb = AL((size_t)4096*4608*8); oQ8Ib = AL((size_t)4096*4608);
        oQ8Xb = AL((size_t)4096*1152);   oDSXb = AL(4096*8); oDSIb = AL(4096*8);
        if (off <= ws_size) schunk = 4096;
        else {
            off = off_w8;
            oINTb = AL((size_t)2048*4608*8); oQ8Ib = AL((size_t)2048*4608); oDSIb = AL(2048*8);
            if (off <= ws_size) schunk = 2048;
            else off = off_w8;
        }
    }

    char* w8p = (char*)d_ws;
    double* scales = (double*)(w8p + oScale);
    double* parts  = (double*)(w8p + oPart);
    double* probeD = (double*)(w8p + oProbe);
    int*    mflag  = (int*)(w8p + oFlag);
    double *SM1=(double*)(w8p+oSM1), *SM2=(double*)(w8p+oSM2), *SM3=(double*)(w8p+oSM3);
    double *CB=(double*)(w8p+oCB), *MOD=(double*)(w8p+oMOD);
    double *H=(double*)(w8p+oH), *INT=(double*)(w8p+oINT);
    double *F0=(double*)(w8p+oF0), *XT=(double*)(w8p+oXT);
    double *FB=(double*)(w8p+oFB), *IB=(double*)(w8p+oIB), *GB=(double*)(w8p+oGB);
    double *GB2=(double*)(w8p+oGB2);
    double *FBr=(double*)(w8p+oFBr), *IBr=(double*)(w8p+oIBr), *GBr=(double*)(w8p+oGBr);
    double *ACC=F0, *OB=H, *RO=(double*)(w8p+oRO);
    double *FB2 = INT, *IB2 = INT + (size_t)2048*1152;          // base INT reuse
    double *MVB = FB2;                                          // free after scans
    double *OBs = OB, *OBm = OB + (size_t)2048*1152;
    double *OBr = OB + (size_t)4096*1152;
    signed char *Q8X=(signed char*)(w8p+oQ8X), *Q8I=(signed char*)(w8p+oQ8I);
    signed char *Q8O=(signed char*)(w8p+oQ8O), *Q8O2=(signed char*)(w8p+oQ8O2);
    signed char *Q8R=(signed char*)(w8p+oQ8R);
    signed char *Q8T=(signed char*)(w8p+oQ8T), *Q8C=(signed char*)(w8p+oQ8C);
    double *DSX=(double*)(w8p+oDSX), *DSI=(double*)(w8p+oDSI), *DSO=(double*)(w8p+oDSO);
    double *DSO2=(double*)(w8p+oDSO2);
    double *DSR=(double*)(w8p+oDSR), *DST=(double*)(w8p+oDST), *DSC=(double*)(w8p+oDSC);
    signed char* W8 = (signed char*)(w8p + oW8);
    float* Wt = (float*)(w8p + oWt);

    double*      INTs = (schunk > 1024) ? (double*)(w8p + oINTb) : INT;
    signed char* Q8Is = (schunk > 1024) ? (signed char*)(w8p + oQ8Ib) : Q8I;
    double*      DSIs = (schunk > 1024) ? (double*)(w8p + oDSIb) : DSI;
    signed char* Q8Xs = (schunk == 4096) ? (signed char*)(w8p + oQ8Xb) : Q8X;
    double*      DSXs = (schunk == 4096) ? (double*)(w8p + oDSXb) : DSX;

    // ---------- probe + scales + ternarize + dc-w transpose ----------
    k_mfma64_probe<<<1, 64, 0, stream>>>(probeD);
    k_mfma64_check<<<1, 64, 0, stream>>>(probeD, mflag);
    k_abssum_all<<<dim3(32,37), 256, 0, stream>>>(wl, parts);
    k_abssum_fin<<<37, 64, 0, stream>>>(parts, scales);
    if (useW8)
        k_ternarize<<<dim3(64,37), 256, 0, stream>>>(wl, wo, scales, W8);
    if (useWt)
        k_dcw_prep<<<1152, 256, 0, stream>>>(sa_dc_w, Wt);

    // ---------- launch helpers ----------
    auto qgemm = [&](const signed char* A8, const double* as, const float* Win, int slot,
                     const float* b, double* Cout, int M, int N, int K, int accum){
        int gm = (M+127)/128, gn = (N+127)/128;
        if (useW8)
            k_qgemm<0,1><<<gm*gn, 256, 0, stream>>>(A8, as, Win, W8 + wo.o[slot],
                                                    scales+slot, wn[slot], b, Cout, M, N, K, accum, gm);
        else
            k_qgemm<0,0><<<gm*gn, 256, 0, stream>>>(A8, as, Win, nullptr,
                                                    scales+slot, wn[slot], b, Cout, M, N, K, accum, gm);
    };
    auto qgemmGate = [&](const signed char* A8, const double* as, const float* Win, int slot,
                         double* Cout, int M){
        int gm = (M+127)/128;
        if (useW8)
            k_qgemm<1,1><<<gm*36, 256, 0, stream>>>(A8, as, Win, W8 + wo.o[slot],
                                                    scales+slot, wn[slot], nullptr, Cout, M, 4608, 1152, 0, gm);
        else
            k_qgemm<1,0><<<gm*36, 256, 0, stream>>>(A8, as, Win, nullptr,
                                                    scales+slot, wn[slot], nullptr, Cout, M, 4608, 1152, 0, gm);
    };
    auto fig = [&](const signed char* A8, const double* as, int sF, int sI, int sG,
                   const float* wF, const float* wI, const float* wG, int M,
                   int n_outer, long long ostr, int n_inner, long long tstr, int Tlen){
        if (useW8) {
            W3 w3{ {W8+wo.o[sF], W8+wo.o[sI], W8+wo.o[sG]},
                   {scales+sF, scales+sI, scales+sG},
                   {FB, IB, GB} };
            int gm = M/128;
            k_qgemm3<<<gm*27, 256, 0, stream>>>(A8, as, w3, 1327104, M, gm);
            long long nch = (long long)n_outer*n_inner;
            k_scan3<<<(unsigned)((nch+255)/256), 256, 0, stream>>>(FB, IB, OB, n_outer, ostr, n_inner, tstr, Tlen);
        } else {
            qgemm(A8, as, wF, sF, nullptr, FB, M, 1152, 1152, 0);
            qgemm(A8, as, wI, sI, nullptr, IB, M, 1152, 1152, 0);
            qgemm(A8, as, wG, sG, nullptr, GB, M, 1152, 1152, 0);
            long long nel = (long long)M*1152;
            k_gatepre<<<(unsigned)((nel+255)/256), 256, 0, stream>>>(FB, IB, nel);
            long long nch = (long long)n_outer*n_inner;
            k_scan2<<<(unsigned)((nch+255)/256), 256, 0, stream>>>(FB, IB, OB, n_outer, ostr, n_inner, tstr, Tlen);
        }
    };
    auto rsq8big = [&](const double* xi, signed char* q8, double* ds, int M){
        if (useW8) k_rsq8c<<<M, 256, 4608*8, stream>>>(xi, q8, ds, 4608);
        else       k_rsq8<double><<<M, 256, 0, stream>>>(xi, q8, ds, 4608, 0);
    };

    // ---------- conditioning vector c ----------
    k_temb<<<8, 128, 0, stream>>>(T, SM1);
    k_rsq8<double><<<8, 256, 0, stream>>>(SM1, Q8T, DST, 256, 0);
    qgemm(Q8T, DST, te_w1, 0, te_b1, SM3, 8, 1152, 256, 0);
    k_rsq8<double><<<8, 256, 0, stream>>>(SM3, Q8T, DST, 1152, 1);
    qgemm(Q8T, DST, te_w2, 1, te_b2, SM2, 8, 1152, 1152, 0);
    k_rsq8<float><<<8, 256, 0, stream>>>(Y, Q8T, DST, 768, 0);
    qgemm(Q8T, DST, pp_w, 2, pp_b, SM3, 8, 1152, 768, 0);
    k_add<<<36, 256, 0, stream>>>(SM2, SM3, CB, 9216);
    k_rsq8<double><<<8, 256, 0, stream>>>(CB, Q8C, DSC, 1152, 1);

    // ---------- spatial adapter: patch embed + block 0 only ----------
    k_dgemm<1,0><<<18*128, 256, 0, stream>>>(XC, sa_pe_w, sa_pe_b, H, 8192, 1152, 1536, 18, mflag);
    {
        const int nch = 8192 / schunk;
        for (int ch = 0; ch < nch; ++ch) {
            double* Hrow = H + (size_t)ch*schunk*1152;
            k_lnq8<<<schunk, 256, 1152*8, stream>>>(Hrow, Q8Xs, DSXs, 1152, sa_ln_g, sa_ln_b,
                                                    nullptr, nullptr, 0, 1e-5);
            qgemmGate(Q8Xs, DSXs, sa_gate_w, 3, INTs, schunk);
            rsq8big(INTs, Q8Is, DSIs, schunk);
            qgemm(Q8Is, DSIs, sa_down_w, 4, nullptr, Hrow, schunk, 1152, 4608, 0);
        }
    }
    if (useWt)
        k_dgemm<2,0><<<18*32, 256, 0, stream>>>(H, Wt, sa_dc_b, F0, 2048, 1152, 4608, 18, mflag);
    else
        k_dgemm<2,1><<<18*32, 256, 0, stream>>>(H, sa_dc_w, sa_dc_b, F0, 2048, 1152, 4608, 18, mflag);

    // ---------- patchify latents + pos + feats0 ----------
    k_patchify<<<9216, 256, 0, stream>>>(X, xe_w, xe_b, pos, F0, XT);
    k_rsq8<float><<<512, 256, 0, stream>>>(REF, Q8R, DSR, 1152, 0);

    // ---------- transformer blocks ----------
    for (int l = 0; l < 2; ++l) {
        int sb = 5 + l*15;
        const float *wada = ada_w + (size_t)l*7962624, *bada = ada_b + (size_t)l*6912;
        const float *swi = sa_wi + (size_t)l*1327104, *swf = sa_wf + (size_t)l*1327104;
        const float *swg = sa_wg + (size_t)l*1327104, *swo = sa_wo + (size_t)l*1327104;
        const float *mwi = mv_wi + (size_t)l*1327104, *mwf = mv_wf + (size_t)l*1327104;
        const float *mwg = mv_wg + (size_t)l*1327104, *mwo = mv_wo + (size_t)l*1327104;
        const float *rwi = rf_wi + (size_t)l*1327104, *rwf = rf_wf + (size_t)l*1327104;
        const float *rwg = rf_wg + (size_t)l*1327104, *rwo = rf_wo + (size_t)l*1327104;
        const float *wgt = gate_w + (size_t)l*10616832, *wdn = down_w + (size_t)l*5308416;

        qgemm(Q8C, DSC, wada, sb+0, bada, MOD, 8, 6912, 1152, 0);

        k_lnq8<<<2048, 256, 1152*8, stream>>>(XT, Q8X, DSX, 1152, nullptr, nullptr,
                                              MOD+0, MOD+1152, 6912, 1e-6);

        if (useW8) {
            // ---- fused self+mv+ref attention ----
            W9 w9{ {W8+wo.o[sb+2], W8+wo.o[sb+1], W8+wo.o[sb+3],
                    W8+wo.o[sb+6], W8+wo.o[sb+5], W8+wo.o[sb+7],
                    W8+wo.o[sb+10], W8+wo.o[sb+9], W8+wo.o[sb+11]},
                   {scales+sb+2, scales+sb+1, scales+sb+3,
                    scales+sb+6, scales+sb+5, scales+sb+7,
                    scales+sb+10, scales+sb+9, scales+sb+11},
                   {FB, IB, GB, FB2, IB2, GB2, FBr, IBr, GBr} };
            k_qgemm9<<<972, 256, 0, stream>>>(Q8X, DSX, Q8R, DSR, w9, 1327104);
            k_scanc3<<<(9216 + 589824 + 2304 + 255)/256, 256, 0, stream>>>(
                FB, IB, FB2, IB2, FBr, IBr, OBs, OBm, OBr);
            k_ogateq8c3<<<4608, 256, 1152*8, stream>>>(OBs, GB, OBm, GB2, OBr, GBr, Q8O2, DSO2);
            k_qgemmO3<<<324, 256, 0, stream>>>(Q8O2, DSO2,
                                               W8+wo.o[sb+4], W8+wo.o[sb+8], W8+wo.o[sb+12],
                                               scales+sb+4, scales+sb+8, scales+sb+12,
                                               1327104, ACC, MVB, RO);
            k_resid_attn2<<<9216, 256, 0, stream>>>(XT, ACC, MVB, RO, MOD);
        } else {
            // ---- proven sequential path ----
            fig(Q8X, DSX, sb+2, sb+1, sb+3, swf, swi, swg, 2048, 8, 294912LL, 1152, 1152LL, 256);
            k_ogateq8<<<2048, 256, 1152*8, stream>>>(OB, GB, Q8O, DSO, 1152);
            qgemm(Q8O, DSO, swo, sb+4, nullptr, ACC, 2048, 1152, 1152, 0);
            fig(Q8X, DSX, sb+6, sb+5, sb+7, mwf, mwi, mwg, 2048, 2, 1179648LL, 294912, 294912LL, 4);
            k_ogateq8<<<2048, 256, 1152*8, stream>>>(OB, GB, Q8O, DSO, 1152);
            qgemm(Q8O, DSO, mwo, sb+8, nullptr, ACC, 2048, 1152, 1152, 1);
            fig(Q8R, DSR, sb+10, sb+9, sb+11, rwf, rwi, rwg, 512, 2, 294912LL, 1152, 1152LL, 256);
            k_ogateq8<<<512, 256, 1152*8, stream>>>(OB, GB, Q8O, DSO, 1152);
            qgemm(Q8O, DSO, rwo, sb+12, nullptr, RO, 512, 1152, 1152, 0);
            k_resid_attn<<<9216, 256, 0, stream>>>(XT, ACC, RO, MOD);
        }

        // MLP
        k_lnq8<<<2048, 256, 1152*8, stream>>>(XT, Q8X, DSX, 1152, nullptr, nullptr,
                                              MOD+3*1152, MOD+4*1152, 6912, 1e-6);
        if (schunk >= 2048) {
            qgemmGate(Q8X, DSX, wgt, sb+13, INTs, 2048);
            rsq8big(INTs, Q8Is, DSIs, 2048);
            qgemm(Q8Is, DSIs, wdn, sb+14, nullptr, OB, 2048, 1152, 4608, 0);
        } else {
            for (int ch = 0; ch < 2; ++ch) {
                qgemmGate(Q8X + (size_t)ch*1024*1152, DSX + ch*1024, wgt, sb+13, INT, 1024);
                k_rsq8<double><<<1024, 256, 0, stream>>>(INT, Q8I, DSI, 4608, 0);
                qgemm(Q8I, DSI, wdn, sb+14, nullptr, OB + (size_t)ch*1024*1152, 1024, 1152, 4608, 0);
            }
        }
        k_resid_mlp<<<9216, 256, 0, stream>>>(XT, OB, MOD);
    }

    // ---------- final layer + unpatchify ----------
    qgemm(Q8C, DSC, fl_ada_w, 35, fl_ada_b, MOD, 8, 2304, 1152, 0);
    k_lnq8<<<2048, 256, 1152*8, stream>>>(XT, Q8X, DSX, 1152, nullptr, nullptr,
                                          MOD+0, MOD+1152, 2304, 1e-6);
    qgemm(Q8X, DSX, fl_w, 36, fl_b, FB, 2048, 32, 1152, 0);
    k_unpatch<<<256, 256, 0, stream>>>(FB, OUT);
}